// Round 12
// baseline (140.285 us; speedup 1.0000x reference)
//
#include <hip/hip_runtime.h>
#include <stdint.h>
#include <math.h>

typedef unsigned short u16;
typedef unsigned int u32;
typedef __attribute__((ext_vector_type(8))) short bf16x8;   // 8 bf16 (4 VGPRs) MFMA A/B frag
typedef __attribute__((ext_vector_type(4))) float f32x4;
typedef __attribute__((ext_vector_type(2))) float f32x2;
typedef __attribute__((ext_vector_type(2))) u16 u16x2;
typedef __attribute__((ext_vector_type(8))) u16 u16x8;
typedef __attribute__((ext_vector_type(2))) u32 u32x2;

#define B_ 8
#define T_ 1024
#define D_ 512
#define H_ 8
#define TP1 1025
// q scale: 1/sqrt(64) * log2(e)  (softmax runs in exp2 domain)
#define QSCALE 0.1803368801111204f

__device__ __forceinline__ u16 f2b(float f) {           // f32 -> bf16 RNE
  union { float f; u32 u; } v; v.f = f;
  return (u16)((v.u + 0x7fffu + ((v.u >> 16) & 1u)) >> 16);
}
__device__ __forceinline__ void gld16(const void* g, void* l) {
  // async global->LDS, 16B/lane; LDS dest = wave-uniform base + lane*16
  __builtin_amdgcn_global_load_lds((const __attribute__((address_space(1))) u32*)g,
                                   (__attribute__((address_space(3))) u32*)l, 16, 0, 0);
}
__device__ __forceinline__ f32x4 mfma16(bf16x8 a, bf16x8 b, f32x4 c) {
  return __builtin_amdgcn_mfma_f32_16x16x32_bf16(a, b, c, 0, 0, 0);
}
__device__ __forceinline__ u32 cvtpk(float lo, float hi) {   // 2xf32 -> packed bf16x2 (RNE)
  u32 r;
  asm("v_cvt_pk_bf16_f32 %0, %1, %2" : "=v"(r) : "v"(lo), "v"(hi));
  return r;
}
union U8 { u32 u[4]; bf16x8 v; };

// counted-vmcnt waits: wait for the OLDEST stage only, keep the rest in flight
#define WAITV(N) asm volatile("s_waitcnt vmcnt(" #N ")" ::: "memory")

// ---------------- fused prep: tiled (coalesced) weight transposes + rope tables ----------------
__global__ __launch_bounds__(256) void prep_kernel(const float* __restrict__ W_attn,
    const float* __restrict__ W1, const float* __restrict__ W2,
    const float* __restrict__ seq,
    u16* __restrict__ WtA, u16* __restrict__ W1i, u16* __restrict__ W2t,
    float* __restrict__ cq, float* __restrict__ sq_,
    float* __restrict__ ck, float* __restrict__ sk) {
  int bid = blockIdx.x, tid = threadIdx.x;
  if (bid >= 576) {                        // rope: B*T*16 elements
    int i = (bid - 576) * 256 + tid;
    int p = i & 15, bt = i >> 4, b = bt >> 10, t = bt & 1023;
    float inv = expf(-(float)p * 0.5756462732485115f);   // 10000^(-p/16)
    float aq = seq[b * TP1 + t] * inv;
    float ak = seq[b * TP1 + t + 1] * inv;
    cq[i] = cosf(aq); sq_[i] = sinf(aq);
    ck[i] = cosf(ak); sk[i] = sinf(ak);
    return;
  }
  __shared__ u16 lt[64][65];
  const float* src; u16* dst; int ld, Kd, k0, r0; bool ilv = false;
  if (bid < 192) {            // WtA: 8 k-tiles x 24 n-tiles
    src = W_attn; dst = WtA; ld = 1536; Kd = 512;
    k0 = (bid & 7) * 64; r0 = (bid >> 3) * 64;
  } else if (bid < 448) {     // W1i: 8 k-tiles x 32 r-tiles, interleaved
    int t = bid - 192;
    src = W1; dst = W1i; ld = 2048; Kd = 512; ilv = true;
    k0 = (t & 7) * 64; r0 = (t >> 3) * 64;
  } else {                    // W2t: 16 k-tiles x 8 n-tiles
    int t = bid - 448;
    src = W2; dst = W2t; ld = 512; Kd = 1024;
    k0 = (t & 15) * 64; r0 = (t >> 4) * 64;
  }
  int nl = tid & 63;
  int scol, rloc;
  if (ilv) {
    if (nl < 32) { scol = (r0 >> 1) + nl;          rloc = ((nl >> 4) << 5) + (nl & 15); }
    else         { scol = 1024 + (r0 >> 1) + (nl - 32); rloc = (((nl - 32) >> 4) << 5) + 16 + (nl & 15); }
  } else { scol = r0 + nl; rloc = nl; }
  #pragma unroll
  for (int it = 0; it < 16; it++) {
    int kl = (tid >> 6) * 16 + it;
    lt[rloc][kl] = f2b(src[(size_t)(k0 + kl) * ld + scol]);
  }
  __syncthreads();
  #pragma unroll
  for (int it = 0; it < 16; it++) {
    int rl = (tid >> 6) * 16 + it;
    dst[(size_t)(r0 + rl) * Kd + k0 + nl] = lt[rl][nl];
  }
}

// ---------------- LayerNorm: one WAVE per row, no LDS, no barriers ----------------
__global__ __launch_bounds__(256) void ln_kernel(const float* __restrict__ x,
    const float* __restrict__ g, const float* __restrict__ bta, u16* __restrict__ out) {
  int row = blockIdx.x * 4 + (threadIdx.x >> 6);    // 8192 rows, 4 rows/block
  int lane = threadIdx.x & 63;
  const float* xr = x + (size_t)row * D_ + lane * 8;
  f32x4 v0 = *(const f32x4*)xr;
  f32x4 v1 = *(const f32x4*)(xr + 4);
  float s = 0.f, sq = 0.f;
  #pragma unroll
  for (int j = 0; j < 4; j++) { s += v0[j] + v1[j]; sq += v0[j] * v0[j] + v1[j] * v1[j]; }
  #pragma unroll
  for (int m = 1; m < 64; m <<= 1) { s += __shfl_xor(s, m); sq += __shfl_xor(sq, m); }
  float mean = s * (1.f / D_);
  float var = sq * (1.f / D_) - mean * mean;
  float rstd = rsqrtf(var + 1e-5f);
  f32x4 g0 = *(const f32x4*)(g + lane * 8);
  f32x4 g1 = *(const f32x4*)(g + lane * 8 + 4);
  f32x4 b0 = *(const f32x4*)(bta + lane * 8);
  f32x4 b1 = *(const f32x4*)(bta + lane * 8 + 4);
  u16x8 o;
  #pragma unroll
  for (int j = 0; j < 4; j++) {
    o[j]     = f2b((v0[j] - mean) * rstd * g0[j] + b0[j]);
    o[4 + j] = f2b((v1[j] - mean) * rstd * g1[j] + b1[j]);
  }
  *(u16x8*)(out + (size_t)row * D_ + lane * 8) = o;
}

// ---------------- QKV GEMM: 128x128, 512 thr / 8 waves (ff2 structure), 3-deep ----------------
// Wave (wm,wn) of 2x4 owns a 64x32 sub-tile; stage = 1 gld16 per operand.
// Fused epilogue: type-emb + RoPE + scale + head layout.
__global__ __launch_bounds__(512) void gemm_qkv(const u16* __restrict__ A,
    const u16* __restrict__ Bt,
    const int* __restrict__ x_type, const float* __restrict__ type_emb,
    const float* __restrict__ rqc, const float* __restrict__ rqs,
    const float* __restrict__ rkc, const float* __restrict__ rks,
    u16* __restrict__ qT, u16* __restrict__ kT, u16* __restrict__ vT) {
  __shared__ u16 lA[3][4096];
  __shared__ u16 lB[3][4096];
  const int K = 512, NK = 16;
  const int tid = threadIdx.x, lane = tid & 63, w = tid >> 6;   // 8 waves
  const int wm = w >> 2, wn = w & 3;                            // 2x4: 64x32 per wave
  int swz = (blockIdx.x & 7) * 96 + (blockIdx.x >> 3);
  int byy = swz / 12, bxx = swz - byy * 12;
  const size_t bm = (size_t)byy * 128;
  const size_t bn = (size_t)bxx * 128;

  const int r0 = tid >> 2;                                      // 0..127
  const int cs = ((tid & 3) ^ ((r0 >> 1) & 3)) * 8;
  const u16* a0 = A + (bm + r0) * K + cs;
  const u16* b0 = Bt + (bn + r0) * K + cs;

  int aoff[4], boff[2];
  #pragma unroll
  for (int i = 0; i < 4; i++) {
    int ra = wm * 64 + i * 16 + (lane & 15);
    aoff[i] = ra * 64 + (((lane >> 4) ^ ((ra >> 1) & 3)) * 16);
  }
  #pragma unroll
  for (int n = 0; n < 2; n++) {
    int rb = wn * 32 + n * 16 + (lane & 15);
    boff[n] = rb * 64 + (((lane >> 4) ^ ((rb >> 1) & 3)) * 16);
  }

  auto stage = [&](int j, int buf) {      // 2 loads (512 thr cover full 8KB tiles)
    gld16(a0 + j * 32, (char*)lA + buf * 8192 + w * 1024);
    gld16(b0 + j * 32, (char*)lB + buf * 8192 + w * 1024);
  };
  f32x4 acc[4][2] = {};
  auto compute = [&](int buf) {
    const char* lAc = (const char*)lA + buf * 8192;
    const char* lBc = (const char*)lB + buf * 8192;
    bf16x8 af[4], bf[2];
    #pragma unroll
    for (int i = 0; i < 4; i++) af[i] = *(const bf16x8*)(lAc + aoff[i]);
    #pragma unroll
    for (int n = 0; n < 2; n++) bf[n] = *(const bf16x8*)(lBc + boff[n]);
    __builtin_amdgcn_s_setprio(1);
    #pragma unroll
    for (int i = 0; i < 4; i++)
      #pragma unroll
      for (int n = 0; n < 2; n++)
        acc[i][n] = mfma16(af[i], bf[n], acc[i][n]);
    __builtin_amdgcn_s_setprio(0);
  };

  stage(0, 0);
  stage(1, 1);
  int cur = 0;
  for (int j = 0; j < NK - 1; j++) {
    WAITV(2);
    __builtin_amdgcn_s_barrier();
    if (j + 2 < NK) { int nb = cur + 2; if (nb >= 3) nb -= 3; stage(j + 2, nb); }
    compute(cur);
    cur = (cur + 1 == 3) ? 0 : cur + 1;
  }
  WAITV(0);
  __builtin_amdgcn_s_barrier();
  compute(cur);

  // fused epilogue. block-uniform region: 0=q (cols 0..511), 1=k, 2=v
  const int region = (int)(bn >> 9);
  #pragma unroll
  for (int i = 0; i < 4; i++) {
    #pragma unroll
    for (int jj = 0; jj < 4; jj++) {
      int row = (int)bm + wm * 64 + i * 16 + (lane >> 4) * 4 + jj;   // bt index
      int b = row >> 10, t = row & 1023;
      if (region == 0) {
        int ty = x_type[b * TP1 + t];
        #pragma unroll
        for (int n = 0; n < 2; n++) {
          int cloc = (int)bn + wn * 32 + n * 16 + (lane & 15);       // 0..511
          int h = cloc >> 6, hd = cloc & 63;
          float v = acc[i][n][jj] + type_emb[(size_t)ty * 1024 + cloc];
          float vp = __shfl_xor(v, 1);
          if (hd < 32) {
            int p = hd >> 1;
            float c = rqc[row * 16 + p], s = rqs[row * 16 + p];
            v = (hd & 1) ? (v * c + vp * s) : (v * c - vp * s);
          }
          qT[((size_t)(b * 8 + h) * T_ + t) * 64 + hd] = f2b(v * QSCALE);
        }
      } else if (region == 1) {
        int ty = x_type[b * TP1 + t + 1];
        #pragma unroll
        for (int n = 0; n < 2; n++) {
          int cloc = (int)bn - 512 + wn * 32 + n * 16 + (lane & 15); // 0..511
          int h = cloc >> 6, hd = cloc & 63;
          float v = acc[i][n][jj] + type_emb[(size_t)ty * 1024 + 512 + cloc];
          float vp = __shfl_xor(v, 1);
          if (hd < 32) {
            int p = hd >> 1;
            float c = rkc[row * 16 + p], s = rks[row * 16 + p];
            v = (hd & 1) ? (v * c + vp * s) : (v * c - vp * s);
          }
          kT[((size_t)(b * 8 + h) * T_ + t) * 64 + hd] = f2b(v);
        }
      } else {
        #pragma unroll
        for (int n = 0; n < 2; n++) {
          int cloc = (int)bn - 1024 + wn * 32 + n * 16 + (lane & 15);
          int h = cloc >> 6, hd = cloc & 63;
          vT[((size_t)(b * 8 + h) * 64 + hd) * T_ + t] = f2b(acc[i][n][jj]);
        }
      }
    }
  }
}

// ---------------- FF1 GEMM: BM=256 x BN=128, BK=32, 512 thr / 8 waves, 2-phase ----------------
__global__ __launch_bounds__(512) void gemm_ff1(const u16* __restrict__ A,
    const u16* __restrict__ Bt, const float* __restrict__ b1,
    u16* __restrict__ outp) {
  __shared__ u16 lA[2][8192];              // 256 rows x 32 cols per buf (16KB)
  __shared__ u16 lB[2][4096];              // 128 rows x 32 cols per buf (8KB)
  const int K = 512;
  const int tid = threadIdx.x, lane = tid & 63, w = tid >> 6;   // 8 waves
  const int wm = w >> 2, wn = w & 3;
  int swz = (blockIdx.x & 7) * 64 + (blockIdx.x >> 3);          // 512 blocks
  int byy = swz >> 4, bxx = swz & 15;                           // 32 x 16
  const size_t bm = (size_t)byy * 256;
  const size_t bn = (size_t)bxx * 128;

  const int r0 = tid >> 2;                                      // 0..127
  const int cs = ((tid & 3) ^ ((r0 >> 1) & 3)) * 8;
  const u16* a0 = A + (bm + r0) * K + cs;
  const u16* a1 = A + (bm + 128 + r0) * K + cs;
  const u16* b0 = Bt + (bn + r0) * K + cs;

  int aoff[8], boff[2];
  #pragma unroll
  for (int i = 0; i < 8; i++) {
    int ra = wm * 128 + i * 16 + (lane & 15);
    aoff[i] = ra * 64 + (((lane >> 4) ^ ((ra >> 1) & 3)) * 16);
  }
  #pragma unroll
  for (int n = 0; n < 2; n++) {
    int rb = wn * 32 + n * 16 + (lane & 15);
    boff[n] = rb * 64 + (((lane >> 4) ^ ((rb >> 1) & 3)) * 16);
  }

  auto stage = [&](int k0, int buf) {      // 3 gld16 calls (8KB each)
    char* ad = (char*)lA + buf * 16384 + w * 1024;
    char* bd = (char*)lB + buf * 8192 + w * 1024;
    gld16(a0 + k0, ad);                    // A rows 0..127
    gld16(a1 + k0, ad + 8192);             // A rows 128..255
    gld16(b0 + k0, bd);                    // B rows 0..127
  };

  f32x4 acc[8][2] = {};
  stage(0, 0);
  __syncthreads();
  int cur = 0;
  for (int k0 = 0; k0 < K; k0 += 32) {
    if (k0 + 32 < K) stage(k0 + 32, cur ^ 1);
    const char* lAc = (const char*)lA + cur * 16384;
    const char* lBc = (const char*)lB + cur * 8192;
    bf16x8 bf[2];
    #pragma unroll
    for (int n = 0; n < 2; n++) bf[n] = *(const bf16x8*)(lBc + boff[n]);
    __builtin_amdgcn_s_setprio(1);
    #pragma unroll
    for (int i = 0; i < 8; i++) {
      bf16x8 af = *(const bf16x8*)(lAc + aoff[i]);
      acc[i][0] = mfma16(af, bf[0], acc[i][0]);
      acc[i][1] = mfma16(af, bf[1], acc[i][1]);
    }
    __builtin_amdgcn_s_setprio(0);
    __syncthreads();
    cur ^= 1;
  }
  // epilogue: real col c = bn/2 + wn*16 + (lane&15); a = acc[i][0], g = acc[i][1]
  {
    int c = ((int)bn >> 1) + wn * 16 + (lane & 15);
    float bav = b1[c], bgv = b1[1024 + c];
    #pragma unroll
    for (int i = 0; i < 8; i++) {
      #pragma unroll
      for (int jj = 0; jj < 4; jj++) {
        int row = (int)bm + wm * 128 + i * 16 + (lane >> 4) * 4 + jj;
        float av = acc[i][0][jj] + bav;
        float gv = acc[i][1][jj] + bgv;
        float sg = gv / (1.f + expf(-gv));
        outp[(size_t)row * 1024 + c] = f2b(sg * av);
      }
    }
  }
}

// ---------------- FF2 GEMM, 512 thr / 8 waves, 3-deep counted pipeline ----------------
__global__ __launch_bounds__(512) void gemm_ff2(const u16* __restrict__ A,
    const u16* __restrict__ Bt, const float* __restrict__ bias,
    float* __restrict__ C) {
  __shared__ u16 lA[3][4096];
  __shared__ u16 lB[3][4096];
  const int K = 1024, N = 512, NK = 32;
  const int tid = threadIdx.x, lane = tid & 63, w = tid >> 6;   // w 0..7
  const int wm = w >> 2, wn = w & 3;                            // 2x4 waves: 64x32 each
  int swz = (blockIdx.x & 7) * 32 + (blockIdx.x >> 3);          // 256 blocks
  int byy = swz >> 2, bxx = swz & 3;
  const size_t bm = (size_t)byy * 128;
  const size_t bn = (size_t)bxx * 128;

  const int r0 = tid >> 2;                                      // 0..127
  const int cs = ((tid & 3) ^ ((r0 >> 1) & 3)) * 8;
  const u16* a0 = A + (bm + r0) * K + cs;
  const u16* b0 = Bt + (bn + r0) * K + cs;

  int aoff[4], boff[2];
  #pragma unroll
  for (int i = 0; i < 4; i++) {
    int ra = wm * 64 + i * 16 + (lane & 15);
    aoff[i] = ra * 64 + (((lane >> 4) ^ ((ra >> 1) & 3)) * 16);
  }
  #pragma unroll
  for (int n = 0; n < 2; n++) {
    int rb = wn * 32 + n * 16 + (lane & 15);
    boff[n] = rb * 64 + (((lane >> 4) ^ ((rb >> 1) & 3)) * 16);
  }

  auto stage = [&](int j, int buf) {      // 2 loads
    gld16(a0 + j * 32, (char*)lA + buf * 8192 + w * 1024);
    gld16(b0 + j * 32, (char*)lB + buf * 8192 + w * 1024);
  };
  f32x4 acc[4][2] = {};
  auto compute = [&](int buf) {
    const char* lAc = (const char*)lA + buf * 8192;
    const char* lBc = (const char*)lB + buf * 8192;
    bf16x8 af[4], bf[2];
    #pragma unroll
    for (int i = 0; i < 4; i++) af[i] = *(const bf16x8*)(lAc + aoff[i]);
    #pragma unroll
    for (int n = 0; n < 2; n++) bf[n] = *(const bf16x8*)(lBc + boff[n]);
    __builtin_amdgcn_s_setprio(1);
    #pragma unroll
    for (int i = 0; i < 4; i++)
      #pragma unroll
      for (int n = 0; n < 2; n++)
        acc[i][n] = mfma16(af[i], bf[n], acc[i][n]);
    __builtin_amdgcn_s_setprio(0);
  };

  stage(0, 0);
  stage(1, 1);
  int cur = 0;
  for (int j = 0; j < NK - 1; j++) {
    WAITV(2);
    __builtin_amdgcn_s_barrier();
    if (j + 2 < NK) { int nb = cur + 2; if (nb >= 3) nb -= 3; stage(j + 2, nb); }
    compute(cur);
    cur = (cur + 1 == 3) ? 0 : cur + 1;
  }
  WAITV(0);
  __builtin_amdgcn_s_barrier();
  compute(cur);

  #pragma unroll
  for (int i = 0; i < 4; i++) {
    size_t mrow = bm + wm * 64 + i * 16 + (lane >> 4) * 4;
    #pragma unroll
    for (int n = 0; n < 2; n++) {
      size_t col = bn + wn * 32 + n * 16 + (lane & 15);
      float bv = bias[col];
      #pragma unroll
      for (int jj = 0; jj < 4; jj++) {
        size_t idx = (mrow + jj) * (size_t)N + col;
        C[idx] = acc[i][n][jj] + bv + C[idx];   // in-place residual
      }
    }
  }
}

// ---------------- causal flash attention + residual: out = x_value + attn ----------------
// 8 waves / 512 thr / 128 q-rows, 2-phase LDS dbuf with KVBLK=128 (two proven 8KB
// sub-tiles per buffer): jmax = qp+1 barrier-locked iterations (max 8).
__global__ __launch_bounds__(512, 4) void attn_kernel(const u16* __restrict__ qT,
    const u16* __restrict__ kT, const u16* __restrict__ vT,
    const float* __restrict__ xv, float* __restrict__ X) {
  int s0 = (blockIdx.x & 7) * 64 + (blockIdx.x >> 3);   // 512 blocks, 8 bh per XCD
  const int bh = ((blockIdx.x & 7) << 3) + (s0 & 7);    // 8 bh per XCD
  const int qp = 7 - ((s0 >> 3) & 7);                   // true LPT: qp=7 of all bh first
  const int b = bh >> 3, h = bh & 7;
  const int tid = threadIdx.x, lane = tid & 63, w = tid >> 6;   // 8 waves
  const int q = lane & 15, g = lane >> 4;
  __shared__ u16 lK[2][8192];              // [buf][half0 8KB | half1 8KB]
  __shared__ u16 lV[2][8192];

  const int qrow0 = qp * 128 + w * 16;     // this wave's 16-row q-strip
  bf16x8 qf[2];
  {
    const u16* qp_ = qT + ((size_t)bh * T_ + qrow0 + q) * 64 + g * 8;
    qf[0] = *(const bf16x8*)qp_;
    qf[1] = *(const bf16x8*)(qp_ + 32);
  }
  f32x4 acc[4] = {};
  float mr = -1e30f, lr = 0.f;

  const int sr = tid >> 3;                 // 0..63
  const int scs = ((tid & 7) ^ (sr & 7)) * 8;
  const u16* kb = kT + ((size_t)bh * T_ + sr) * 64 + scs;
  const u16* vb = vT + ((size_t)bh * 64 + sr) * T_ + scs;

  auto stage = [&](int j, int buf) {       // K rows [j*128,+128), V cols [j*128,+128)
    char* kd = (char*)lK + buf * 16384 + w * 1024;
    char* vd = (char*)lV + buf * 16384 + w * 1024;
    gld16(kb + (size_t)j * 8192, kd);              // K half0 (rows +0..63)
    gld16(kb + (size_t)j * 8192 + 4096, kd + 8192);// K half1 (rows +64..127)
    gld16(vb + j * 128, vd);                       // V half0 (cols +0..63)
    gld16(vb + j * 128 + 64, vd + 8192);           // V half1 (cols +64..127)
  };

  const int jmax = qp + 1;
  stage(0, 0);
  __syncthreads();
  int cur = 0;
  for (int j = 0; j < jmax; j++) {
    if (j + 1 < jmax) stage(j + 1, cur ^ 1);   // prefetch next 128-tile under compute
    const char* lKc = (const char*)lK + cur * 16384;
    const char* lVc = (const char*)lV + cur * 16384;

    // QK^T swapped: s[n][i] = S[key = j*128 + n*16+g*4+i][qrow0+q]
    f32x4 s[8] = {};
    __builtin_amdgcn_s_setprio(1);
    #pragma unroll
    for (int ka = 0; ka < 2; ka++) {
      #pragma unroll
      for (int n = 0; n < 8; n++) {
        bf16x8 kf = *(const bf16x8*)(lKc + (n >> 2) * 8192 + ((n & 3) * 16 + q) * 128 +
                                     (((ka * 4 + g) ^ (q & 7)) * 16));
        s[n] = mfma16(kf, qf[ka], s[n]);
      }
    }
    __builtin_amdgcn_s_setprio(0);
    if (j == jmax - 1) {                   // diagonal-tile causal mask
      int qrow = w * 16 + q;               // key-local: n*16+g*4+i > w*16+q
      #pragma unroll
      for (int n = 0; n < 8; n++)
        #pragma unroll
        for (int i = 0; i < 4; i++)
          if (n * 16 + g * 4 + i > qrow) s[n][i] = -1e30f;
    }
    // in-register softmax: one q-row per lane (+2 shfl across g-groups)
    float mt = -1e30f;
    #pragma unroll
    for (int n = 0; n < 8; n++)
      mt = fmaxf(mt, fmaxf(fmaxf(s[n][0], s[n][1]), fmaxf(s[n][2], s[n][3])));
    mt = fmaxf(mt, __shfl_xor(mt, 16));
    mt = fmaxf(mt, __shfl_xor(mt, 32));
    if (__any(mt > mr + 8.f)) {            // defer-max: skip rescale when growth < 2^8
      float mnew = fmaxf(mr, mt);
      float sc = exp2f(mr - mnew);
      mr = mnew;
      lr *= sc;
      #pragma unroll
      for (int t = 0; t < 4; t++) acc[t] *= sc;
    }
    float ps = 0.f;
    U8 pa[4];                              // pa[kt] covers keys kt*32..kt*32+31
    #pragma unroll
    for (int kt = 0; kt < 4; kt++) {
      float p0[4], p1[4];
      #pragma unroll
      for (int i = 0; i < 4; i++) {
        p0[i] = exp2f(s[2 * kt][i] - mr);
        p1[i] = exp2f(s[2 * kt + 1][i] - mr);
        ps += p0[i] + p1[i];
      }
      pa[kt].u[0] = cvtpk(p0[0], p0[1]);
      pa[kt].u[1] = cvtpk(p0[2], p0[3]);
      pa[kt].u[2] = cvtpk(p1[0], p1[1]);
      pa[kt].u[3] = cvtpk(p1[2], p1[3]);
    }
    ps += __shfl_xor(ps, 16);
    ps += __shfl_xor(ps, 32);
    lr += ps;
    // PV: O^T[d][q] += V^T[d][k'] P^T[k'][q]; kt half = kt>>1, sub-chunk = kt&1
    __builtin_amdgcn_s_setprio(1);
    #pragma unroll
    for (int t = 0; t < 4; t++) {
      #pragma unroll
      for (int kt = 0; kt < 4; kt++) {
        const char* vrh = lVc + (kt >> 1) * 8192 + (t * 16 + q) * 128 + (g & 1) * 8;
        int ktl = kt & 1;
        u32x2 lo = *(const u32x2*)(vrh + (((ktl * 4 + (g >> 1)) ^ (q & 7)) * 16));
        u32x2 hi = *(const u32x2*)(vrh + (((ktl * 4 + 2 + (g >> 1)) ^ (q & 7)) * 16));
        U8 af;
        af.u[0] = lo[0]; af.u[1] = lo[1]; af.u[2] = hi[0]; af.u[3] = hi[1];
        acc[t] = mfma16(af.v, pa[kt].v, acc[t]);
      }
    }
    __builtin_amdgcn_s_setprio(0);
    __syncthreads();                       // drains prefetch; publishes buf cur^1
    cur ^= 1;
  }
  // epilogue: lane owns q-row (qrow0+q), cols d = t*16+g*4+{0..3} -> f32x4
  {
    float inv = 1.f / lr;
    size_t base = ((size_t)b * T_ + qrow0 + q) * D_ + h * 64 + g * 4;
    #pragma unroll
    for (int t = 0; t < 4; t++) {
      f32x4 r = *(const f32x4*)(xv + base + t * 16);
      f32x4 o;
      #pragma unroll
      for (int i = 0; i < 4; i++) o[i] = r[i] + acc[t][i] * inv;
      *(f32x4*)(X + base + t * 16) = o;
    }
  }
}

// ------------------------------- launch -------------------------------
extern "C" void kernel_launch(void* const* d_in, const int* in_sizes, int n_in,
                              void* d_out, int out_size, void* d_ws, size_t ws_size,
                              hipStream_t stream) {
  const int*   x_type   = (const int*)d_in[0];
  const float* x_value  = (const float*)d_in[1];
  const float* seq      = (const float*)d_in[2];
  const float* W_attn   = (const float*)d_in[3];
  const float* type_emb = (const float*)d_in[4];
  const float* ln1_g    = (const float*)d_in[5];
  const float* ln1_b    = (const float*)d_in[6];
  const float* ln2_g    = (const float*)d_in[7];
  const float* ln2_b    = (const float*)d_in[8];
  const float* W1       = (const float*)d_in[9];
  const float* b1       = (const float*)d_in[10];
  const float* W2       = (const float*)d_in[11];
  const float* b2       = (const float*)d_in[12];
  float* out = (float*)d_out;
  char* ws = (char*)d_ws;

  // workspace layout — total ~38.5 MiB
  u16*   WtA  = (u16*)(ws + 0);             // 1536x512 bf16  1.5 MiB
  u16*   W1i  = (u16*)(ws + 1572864);       // 2048x512 bf16 interleaved a/gate  2 MiB
  u16*   W2t  = (u16*)(ws + 3670016);       // 512x1024 bf16  1 MiB
  float* rqc  = (float*)(ws + 4718592);     // 4 rope tables, 512 KiB each
  float* rqs  = (float*)(ws + 5242880);
  float* rkc  = (float*)(ws + 5767168);
  float* rks  = (float*)(ws + 6291456);
  u16*   hbuf = (u16*)(ws + 6815744);       // 8192x512 bf16 (h, then h2)  8 MiB
  u16*   qTb  = (u16*)(ws + 15204352);      // (B,H,T,64) bf16  8 MiB
  u16*   kTb  = (u16*)(ws + 23592960);      // 8 MiB
  u16*   vTb  = (u16*)(ws + 31981568);      // (B,H,64,T) bf16  8 MiB
  u16*   ff1a = (u16*)(ws + 15204352);      // 8192x1024 bf16 16 MiB, aliases qT+kT (dead post-attn)

  prep_kernel<<<1088, 256, 0, stream>>>(W_attn, W1, W2, seq, WtA, W1i, W2t,
                                        rqc, rqs, rkc, rks);
  ln_kernel<<<B_ * T_ / 4, 256, 0, stream>>>(x_value, ln1_g, ln1_b, hbuf);
  gemm_qkv<<<768, 512, 0, stream>>>(hbuf, WtA, x_type, type_emb,
                                    rqc, rqs, rkc, rks, qTb, kTb, vTb);
  attn_kernel<<<512, 512, 0, stream>>>(qTb, kTb, vTb, x_value, out);
  ln_kernel<<<B_ * T_ / 4, 256, 0, stream>>>(out, ln2_g, ln2_b, hbuf);
  gemm_ff1<<<512, 512, 0, stream>>>(hbuf, W1i, b1, ff1a);
  gemm_ff2<<<256, 512, 0, stream>>>(ff1a, W2t, b2, out);
}

// Round 13
// 135.078 us; speedup vs baseline: 1.0385x; 1.0385x over previous
//
#include <hip/hip_runtime.h>
#include <stdint.h>
#include <math.h>

typedef unsigned short u16;
typedef unsigned int u32;
typedef __attribute__((ext_vector_type(8))) short bf16x8;   // 8 bf16 (4 VGPRs) MFMA A/B frag
typedef __attribute__((ext_vector_type(4))) float f32x4;
typedef __attribute__((ext_vector_type(2))) float f32x2;
typedef __attribute__((ext_vector_type(2))) u16 u16x2;
typedef __attribute__((ext_vector_type(8))) u16 u16x8;
typedef __attribute__((ext_vector_type(2))) u32 u32x2;

#define B_ 8
#define T_ 1024
#define D_ 512
#define H_ 8
#define TP1 1025
// q scale: 1/sqrt(64) * log2(e)  (softmax runs in exp2 domain)
#define QSCALE 0.1803368801111204f

__device__ __forceinline__ u16 f2b(float f) {           // f32 -> bf16 RNE
  union { float f; u32 u; } v; v.f = f;
  return (u16)((v.u + 0x7fffu + ((v.u >> 16) & 1u)) >> 16);
}
__device__ __forceinline__ void gld16(const void* g, void* l) {
  // async global->LDS, 16B/lane; LDS dest = wave-uniform base + lane*16
  __builtin_amdgcn_global_load_lds((const __attribute__((address_space(1))) u32*)g,
                                   (__attribute__((address_space(3))) u32*)l, 16, 0, 0);
}
__device__ __forceinline__ f32x4 mfma16(bf16x8 a, bf16x8 b, f32x4 c) {
  return __builtin_amdgcn_mfma_f32_16x16x32_bf16(a, b, c, 0, 0, 0);
}
__device__ __forceinline__ u32 cvtpk(float lo, float hi) {   // 2xf32 -> packed bf16x2 (RNE)
  u32 r;
  asm("v_cvt_pk_bf16_f32 %0, %1, %2" : "=v"(r) : "v"(lo), "v"(hi));
  return r;
}
union U8 { u32 u[4]; bf16x8 v; };

// counted-vmcnt waits: wait for the OLDEST stage only, keep the rest in flight
#define WAITV(N) asm volatile("s_waitcnt vmcnt(" #N ")" ::: "memory")

// ---------------- fused prep: tiled (coalesced) weight transposes + rope tables ----------------
__global__ __launch_bounds__(256) void prep_kernel(const float* __restrict__ W_attn,
    const float* __restrict__ W1, const float* __restrict__ W2,
    const float* __restrict__ seq,
    u16* __restrict__ WtA, u16* __restrict__ W1i, u16* __restrict__ W2t,
    float* __restrict__ cq, float* __restrict__ sq_,
    float* __restrict__ ck, float* __restrict__ sk) {
  int bid = blockIdx.x, tid = threadIdx.x;
  if (bid >= 576) {                        // rope: B*T*16 elements
    int i = (bid - 576) * 256 + tid;
    int p = i & 15, bt = i >> 4, b = bt >> 10, t = bt & 1023;
    float inv = expf(-(float)p * 0.5756462732485115f);   // 10000^(-p/16)
    float aq = seq[b * TP1 + t] * inv;
    float ak = seq[b * TP1 + t + 1] * inv;
    cq[i] = cosf(aq); sq_[i] = sinf(aq);
    ck[i] = cosf(ak); sk[i] = sinf(ak);
    return;
  }
  __shared__ u16 lt[64][65];
  const float* src; u16* dst; int ld, Kd, k0, r0; bool ilv = false;
  if (bid < 192) {            // WtA: 8 k-tiles x 24 n-tiles
    src = W_attn; dst = WtA; ld = 1536; Kd = 512;
    k0 = (bid & 7) * 64; r0 = (bid >> 3) * 64;
  } else if (bid < 448) {     // W1i: 8 k-tiles x 32 r-tiles, interleaved
    int t = bid - 192;
    src = W1; dst = W1i; ld = 2048; Kd = 512; ilv = true;
    k0 = (t & 7) * 64; r0 = (t >> 3) * 64;
  } else {                    // W2t: 16 k-tiles x 8 n-tiles
    int t = bid - 448;
    src = W2; dst = W2t; ld = 512; Kd = 1024;
    k0 = (t & 15) * 64; r0 = (t >> 4) * 64;
  }
  int nl = tid & 63;
  int scol, rloc;
  if (ilv) {
    if (nl < 32) { scol = (r0 >> 1) + nl;          rloc = ((nl >> 4) << 5) + (nl & 15); }
    else         { scol = 1024 + (r0 >> 1) + (nl - 32); rloc = (((nl - 32) >> 4) << 5) + 16 + (nl & 15); }
  } else { scol = r0 + nl; rloc = nl; }
  #pragma unroll
  for (int it = 0; it < 16; it++) {
    int kl = (tid >> 6) * 16 + it;
    lt[rloc][kl] = f2b(src[(size_t)(k0 + kl) * ld + scol]);
  }
  __syncthreads();
  #pragma unroll
  for (int it = 0; it < 16; it++) {
    int rl = (tid >> 6) * 16 + it;
    dst[(size_t)(r0 + rl) * Kd + k0 + nl] = lt[rl][nl];
  }
}

// ---------------- LayerNorm: one WAVE per row, no LDS, no barriers ----------------
__global__ __launch_bounds__(256) void ln_kernel(const float* __restrict__ x,
    const float* __restrict__ g, const float* __restrict__ bta, u16* __restrict__ out) {
  int row = blockIdx.x * 4 + (threadIdx.x >> 6);    // 8192 rows, 4 rows/block
  int lane = threadIdx.x & 63;
  const float* xr = x + (size_t)row * D_ + lane * 8;
  f32x4 v0 = *(const f32x4*)xr;
  f32x4 v1 = *(const f32x4*)(xr + 4);
  float s = 0.f, sq = 0.f;
  #pragma unroll
  for (int j = 0; j < 4; j++) { s += v0[j] + v1[j]; sq += v0[j] * v0[j] + v1[j] * v1[j]; }
  #pragma unroll
  for (int m = 1; m < 64; m <<= 1) { s += __shfl_xor(s, m); sq += __shfl_xor(sq, m); }
  float mean = s * (1.f / D_);
  float var = sq * (1.f / D_) - mean * mean;
  float rstd = rsqrtf(var + 1e-5f);
  f32x4 g0 = *(const f32x4*)(g + lane * 8);
  f32x4 g1 = *(const f32x4*)(g + lane * 8 + 4);
  f32x4 b0 = *(const f32x4*)(bta + lane * 8);
  f32x4 b1 = *(const f32x4*)(bta + lane * 8 + 4);
  u16x8 o;
  #pragma unroll
  for (int j = 0; j < 4; j++) {
    o[j]     = f2b((v0[j] - mean) * rstd * g0[j] + b0[j]);
    o[4 + j] = f2b((v1[j] - mean) * rstd * g1[j] + b1[j]);
  }
  *(u16x8*)(out + (size_t)row * D_ + lane * 8) = o;
}

// ---------------- QKV GEMM: 128x128, BK=64 (two proven 32-col sub-tiles), 2-phase ----------------
// 4 waves / 256 thr; 8 barrier iterations (was 16); 32 MFMA/wave/iter.
// Fused epilogue: type-emb + RoPE + scale + head layout.
__global__ __launch_bounds__(256) void gemm_qkv(const u16* __restrict__ A,
    const u16* __restrict__ Bt,
    const int* __restrict__ x_type, const float* __restrict__ type_emb,
    const float* __restrict__ rqc, const float* __restrict__ rqs,
    const float* __restrict__ rkc, const float* __restrict__ rks,
    u16* __restrict__ qT, u16* __restrict__ kT, u16* __restrict__ vT) {
  __shared__ u16 lA[2][8192];              // [buf][khalf0 8KB | khalf1 8KB]
  __shared__ u16 lB[2][8192];
  const int K = 512, NJ = 8;
  const int tid = threadIdx.x, lane = tid & 63, w = tid >> 6;
  const int wm = w >> 1, wn = w & 1;
  int swz = (blockIdx.x & 7) * 96 + (blockIdx.x >> 3);
  int byy = swz / 12, bxx = swz - byy * 12;
  const size_t bm = (size_t)byy * 128;
  const size_t bn = (size_t)bxx * 128;

  const int r0 = tid >> 2;
  const int cs = ((tid & 3) ^ ((r0 >> 1) & 3)) * 8;
  const u16* a0 = A + (bm + r0) * K + cs;
  const u16* a1 = A + (bm + 64 + r0) * K + cs;
  const u16* b0 = Bt + (bn + r0) * K + cs;
  const u16* b1p = Bt + (bn + 64 + r0) * K + cs;

  int aoff[4], boff[4];
  #pragma unroll
  for (int i = 0; i < 4; i++) {
    int ra = wm * 64 + i * 16 + (lane & 15);
    aoff[i] = ra * 64 + (((lane >> 4) ^ ((ra >> 1) & 3)) * 16);
    int rb = wn * 64 + i * 16 + (lane & 15);
    boff[i] = rb * 64 + (((lane >> 4) ^ ((rb >> 1) & 3)) * 16);
  }

  auto stage = [&](int j, int buf) {      // BK=64: 8 gld16 (two 32-col sub-tiles)
    #pragma unroll
    for (int kh = 0; kh < 2; kh++) {
      char* ad = (char*)lA + buf * 16384 + kh * 8192 + w * 1024;
      char* bd = (char*)lB + buf * 16384 + kh * 8192 + w * 1024;
      int ko = j * 64 + kh * 32;
      gld16(a0 + ko, ad);
      gld16(a1 + ko, ad + 4096);
      gld16(b0 + ko, bd);
      gld16(b1p + ko, bd + 4096);
    }
  };
  f32x4 acc[4][4] = {};
  auto compute = [&](int buf) {
    #pragma unroll
    for (int kh = 0; kh < 2; kh++) {
      const char* lAc = (const char*)lA + buf * 16384 + kh * 8192;
      const char* lBc = (const char*)lB + buf * 16384 + kh * 8192;
      bf16x8 af[4], bf[4];
      #pragma unroll
      for (int i = 0; i < 4; i++) af[i] = *(const bf16x8*)(lAc + aoff[i]);
      #pragma unroll
      for (int n = 0; n < 4; n++) bf[n] = *(const bf16x8*)(lBc + boff[n]);
      __builtin_amdgcn_s_setprio(1);
      #pragma unroll
      for (int i = 0; i < 4; i++)
        #pragma unroll
        for (int n = 0; n < 4; n++)
          acc[i][n] = mfma16(af[i], bf[n], acc[i][n]);
      __builtin_amdgcn_s_setprio(0);
    }
  };

  stage(0, 0);
  __syncthreads();
  int cur = 0;
  for (int j = 0; j < NJ; j++) {
    if (j + 1 < NJ) stage(j + 1, cur ^ 1);     // prefetch overlaps compute below
    compute(cur);
    __syncthreads();                           // drains prefetch; publishes buf cur^1
    cur ^= 1;
  }

  // fused epilogue. block-uniform region: 0=q (cols 0..511), 1=k, 2=v
  const int region = (int)(bn >> 9);
  #pragma unroll
  for (int i = 0; i < 4; i++) {
    #pragma unroll
    for (int jj = 0; jj < 4; jj++) {
      int row = (int)bm + wm * 64 + i * 16 + (lane >> 4) * 4 + jj;   // bt index
      int b = row >> 10, t = row & 1023;
      if (region == 0) {
        int ty = x_type[b * TP1 + t];
        #pragma unroll
        for (int n = 0; n < 4; n++) {
          int cloc = (int)bn + wn * 64 + n * 16 + (lane & 15);       // 0..511
          int h = cloc >> 6, hd = cloc & 63;
          float v = acc[i][n][jj] + type_emb[(size_t)ty * 1024 + cloc];
          float vp = __shfl_xor(v, 1);
          if (hd < 32) {
            int p = hd >> 1;
            float c = rqc[row * 16 + p], s = rqs[row * 16 + p];
            v = (hd & 1) ? (v * c + vp * s) : (v * c - vp * s);
          }
          qT[((size_t)(b * 8 + h) * T_ + t) * 64 + hd] = f2b(v * QSCALE);
        }
      } else if (region == 1) {
        int ty = x_type[b * TP1 + t + 1];
        #pragma unroll
        for (int n = 0; n < 4; n++) {
          int cloc = (int)bn - 512 + wn * 64 + n * 16 + (lane & 15); // 0..511
          int h = cloc >> 6, hd = cloc & 63;
          float v = acc[i][n][jj] + type_emb[(size_t)ty * 1024 + 512 + cloc];
          float vp = __shfl_xor(v, 1);
          if (hd < 32) {
            int p = hd >> 1;
            float c = rkc[row * 16 + p], s = rks[row * 16 + p];
            v = (hd & 1) ? (v * c + vp * s) : (v * c - vp * s);
          }
          kT[((size_t)(b * 8 + h) * T_ + t) * 64 + hd] = f2b(v);
        }
      } else {
        #pragma unroll
        for (int n = 0; n < 4; n++) {
          int cloc = (int)bn - 1024 + wn * 64 + n * 16 + (lane & 15);
          int h = cloc >> 6, hd = cloc & 63;
          vT[((size_t)(b * 8 + h) * 64 + hd) * T_ + t] = f2b(acc[i][n][jj]);
        }
      }
    }
  }
}

// ---------------- FF1 GEMM: BM=256 x BN=128, BK=32, 512 thr / 8 waves, 2-phase ----------------
__global__ __launch_bounds__(512) void gemm_ff1(const u16* __restrict__ A,
    const u16* __restrict__ Bt, const float* __restrict__ b1,
    u16* __restrict__ outp) {
  __shared__ u16 lA[2][8192];              // 256 rows x 32 cols per buf (16KB)
  __shared__ u16 lB[2][4096];              // 128 rows x 32 cols per buf (8KB)
  const int K = 512;
  const int tid = threadIdx.x, lane = tid & 63, w = tid >> 6;   // 8 waves
  const int wm = w >> 2, wn = w & 3;
  int swz = (blockIdx.x & 7) * 64 + (blockIdx.x >> 3);          // 512 blocks
  int byy = swz >> 4, bxx = swz & 15;                           // 32 x 16
  const size_t bm = (size_t)byy * 256;
  const size_t bn = (size_t)bxx * 128;

  const int r0 = tid >> 2;                                      // 0..127
  const int cs = ((tid & 3) ^ ((r0 >> 1) & 3)) * 8;
  const u16* a0 = A + (bm + r0) * K + cs;
  const u16* a1 = A + (bm + 128 + r0) * K + cs;
  const u16* b0 = Bt + (bn + r0) * K + cs;

  int aoff[8], boff[2];
  #pragma unroll
  for (int i = 0; i < 8; i++) {
    int ra = wm * 128 + i * 16 + (lane & 15);
    aoff[i] = ra * 64 + (((lane >> 4) ^ ((ra >> 1) & 3)) * 16);
  }
  #pragma unroll
  for (int n = 0; n < 2; n++) {
    int rb = wn * 32 + n * 16 + (lane & 15);
    boff[n] = rb * 64 + (((lane >> 4) ^ ((rb >> 1) & 3)) * 16);
  }

  auto stage = [&](int k0, int buf) {      // 3 gld16 calls (8KB each)
    char* ad = (char*)lA + buf * 16384 + w * 1024;
    char* bd = (char*)lB + buf * 8192 + w * 1024;
    gld16(a0 + k0, ad);                    // A rows 0..127
    gld16(a1 + k0, ad + 8192);             // A rows 128..255
    gld16(b0 + k0, bd);                    // B rows 0..127
  };

  f32x4 acc[8][2] = {};
  stage(0, 0);
  __syncthreads();
  int cur = 0;
  for (int k0 = 0; k0 < K; k0 += 32) {
    if (k0 + 32 < K) stage(k0 + 32, cur ^ 1);
    const char* lAc = (const char*)lA + cur * 16384;
    const char* lBc = (const char*)lB + cur * 8192;
    bf16x8 bf[2];
    #pragma unroll
    for (int n = 0; n < 2; n++) bf[n] = *(const bf16x8*)(lBc + boff[n]);
    __builtin_amdgcn_s_setprio(1);
    #pragma unroll
    for (int i = 0; i < 8; i++) {
      bf16x8 af = *(const bf16x8*)(lAc + aoff[i]);
      acc[i][0] = mfma16(af, bf[0], acc[i][0]);
      acc[i][1] = mfma16(af, bf[1], acc[i][1]);
    }
    __builtin_amdgcn_s_setprio(0);
    __syncthreads();
    cur ^= 1;
  }
  // epilogue: real col c = bn/2 + wn*16 + (lane&15); a = acc[i][0], g = acc[i][1]
  {
    int c = ((int)bn >> 1) + wn * 16 + (lane & 15);
    float bav = b1[c], bgv = b1[1024 + c];
    #pragma unroll
    for (int i = 0; i < 8; i++) {
      #pragma unroll
      for (int jj = 0; jj < 4; jj++) {
        int row = (int)bm + wm * 128 + i * 16 + (lane >> 4) * 4 + jj;
        float av = acc[i][0][jj] + bav;
        float gv = acc[i][1][jj] + bgv;
        float sg = gv / (1.f + expf(-gv));
        outp[(size_t)row * 1024 + c] = f2b(sg * av);
      }
    }
  }
}

// ---------------- FF2 GEMM, 512 thr / 8 waves, 3-deep counted pipeline ----------------
__global__ __launch_bounds__(512) void gemm_ff2(const u16* __restrict__ A,
    const u16* __restrict__ Bt, const float* __restrict__ bias,
    float* __restrict__ C) {
  __shared__ u16 lA[3][4096];
  __shared__ u16 lB[3][4096];
  const int K = 1024, N = 512, NK = 32;
  const int tid = threadIdx.x, lane = tid & 63, w = tid >> 6;   // w 0..7
  const int wm = w >> 2, wn = w & 3;                            // 2x4 waves: 64x32 each
  int swz = (blockIdx.x & 7) * 32 + (blockIdx.x >> 3);          // 256 blocks
  int byy = swz >> 2, bxx = swz & 3;
  const size_t bm = (size_t)byy * 128;
  const size_t bn = (size_t)bxx * 128;

  const int r0 = tid >> 2;                                      // 0..127
  const int cs = ((tid & 3) ^ ((r0 >> 1) & 3)) * 8;
  const u16* a0 = A + (bm + r0) * K + cs;
  const u16* b0 = Bt + (bn + r0) * K + cs;

  int aoff[4], boff[2];
  #pragma unroll
  for (int i = 0; i < 4; i++) {
    int ra = wm * 64 + i * 16 + (lane & 15);
    aoff[i] = ra * 64 + (((lane >> 4) ^ ((ra >> 1) & 3)) * 16);
  }
  #pragma unroll
  for (int n = 0; n < 2; n++) {
    int rb = wn * 32 + n * 16 + (lane & 15);
    boff[n] = rb * 64 + (((lane >> 4) ^ ((rb >> 1) & 3)) * 16);
  }

  auto stage = [&](int j, int buf) {      // 2 loads
    gld16(a0 + j * 32, (char*)lA + buf * 8192 + w * 1024);
    gld16(b0 + j * 32, (char*)lB + buf * 8192 + w * 1024);
  };
  f32x4 acc[4][2] = {};
  auto compute = [&](int buf) {
    const char* lAc = (const char*)lA + buf * 8192;
    const char* lBc = (const char*)lB + buf * 8192;
    bf16x8 af[4], bf[2];
    #pragma unroll
    for (int i = 0; i < 4; i++) af[i] = *(const bf16x8*)(lAc + aoff[i]);
    #pragma unroll
    for (int n = 0; n < 2; n++) bf[n] = *(const bf16x8*)(lBc + boff[n]);
    __builtin_amdgcn_s_setprio(1);
    #pragma unroll
    for (int i = 0; i < 4; i++)
      #pragma unroll
      for (int n = 0; n < 2; n++)
        acc[i][n] = mfma16(af[i], bf[n], acc[i][n]);
    __builtin_amdgcn_s_setprio(0);
  };

  stage(0, 0);
  stage(1, 1);
  int cur = 0;
  for (int j = 0; j < NK - 1; j++) {
    WAITV(2);
    __builtin_amdgcn_s_barrier();
    if (j + 2 < NK) { int nb = cur + 2; if (nb >= 3) nb -= 3; stage(j + 2, nb); }
    compute(cur);
    cur = (cur + 1 == 3) ? 0 : cur + 1;
  }
  WAITV(0);
  __builtin_amdgcn_s_barrier();
  compute(cur);

  #pragma unroll
  for (int i = 0; i < 4; i++) {
    size_t mrow = bm + wm * 64 + i * 16 + (lane >> 4) * 4;
    #pragma unroll
    for (int n = 0; n < 2; n++) {
      size_t col = bn + wn * 32 + n * 16 + (lane & 15);
      float bv = bias[col];
      #pragma unroll
      for (int jj = 0; jj < 4; jj++) {
        size_t idx = (mrow + jj) * (size_t)N + col;
        C[idx] = acc[i][n][jj] + bv + C[idx];   // in-place residual
      }
    }
  }
}

// ---------------- causal flash attention + residual: out = x_value + attn ----------------
// 8 waves / 512 thr / 128 q-rows, 2-phase LDS dbuf with KVBLK=128 (two proven 8KB
// sub-tiles per buffer): jmax = qp+1 barrier-locked iterations (max 8).
__global__ __launch_bounds__(512, 4) void attn_kernel(const u16* __restrict__ qT,
    const u16* __restrict__ kT, const u16* __restrict__ vT,
    const float* __restrict__ xv, float* __restrict__ X) {
  int s0 = (blockIdx.x & 7) * 64 + (blockIdx.x >> 3);   // 512 blocks, 8 bh per XCD
  const int bh = ((blockIdx.x & 7) << 3) + (s0 & 7);    // 8 bh per XCD
  const int qp = 7 - ((s0 >> 3) & 7);                   // true LPT: qp=7 of all bh first
  const int b = bh >> 3, h = bh & 7;
  const int tid = threadIdx.x, lane = tid & 63, w = tid >> 6;   // 8 waves
  const int q = lane & 15, g = lane >> 4;
  __shared__ u16 lK[2][8192];              // [buf][half0 8KB | half1 8KB]
  __shared__ u16 lV[2][8192];

  const int qrow0 = qp * 128 + w * 16;     // this wave's 16-row q-strip
  bf16x8 qf[2];
  {
    const u16* qp_ = qT + ((size_t)bh * T_ + qrow0 + q) * 64 + g * 8;
    qf[0] = *(const bf16x8*)qp_;
    qf[1] = *(const bf16x8*)(qp_ + 32);
  }
  f32x4 acc[4] = {};
  float mr = -1e30f, lr = 0.f;

  const int sr = tid >> 3;                 // 0..63
  const int scs = ((tid & 7) ^ (sr & 7)) * 8;
  const u16* kb = kT + ((size_t)bh * T_ + sr) * 64 + scs;
  const u16* vb = vT + ((size_t)bh * 64 + sr) * T_ + scs;

  auto stage = [&](int j, int buf) {       // K rows [j*128,+128), V cols [j*128,+128)
    char* kd = (char*)lK + buf * 16384 + w * 1024;
    char* vd = (char*)lV + buf * 16384 + w * 1024;
    gld16(kb + (size_t)j * 8192, kd);              // K half0 (rows +0..63)
    gld16(kb + (size_t)j * 8192 + 4096, kd + 8192);// K half1 (rows +64..127)
    gld16(vb + j * 128, vd);                       // V half0 (cols +0..63)
    gld16(vb + j * 128 + 64, vd + 8192);           // V half1 (cols +64..127)
  };

  const int jmax = qp + 1;
  stage(0, 0);
  __syncthreads();
  int cur = 0;
  for (int j = 0; j < jmax; j++) {
    if (j + 1 < jmax) stage(j + 1, cur ^ 1);   // prefetch next 128-tile under compute
    const char* lKc = (const char*)lK + cur * 16384;
    const char* lVc = (const char*)lV + cur * 16384;

    // QK^T swapped: s[n][i] = S[key = j*128 + n*16+g*4+i][qrow0+q]
    f32x4 s[8] = {};
    __builtin_amdgcn_s_setprio(1);
    #pragma unroll
    for (int ka = 0; ka < 2; ka++) {
      #pragma unroll
      for (int n = 0; n < 8; n++) {
        bf16x8 kf = *(const bf16x8*)(lKc + (n >> 2) * 8192 + ((n & 3) * 16 + q) * 128 +
                                     (((ka * 4 + g) ^ (q & 7)) * 16));
        s[n] = mfma16(kf, qf[ka], s[n]);
      }
    }
    __builtin_amdgcn_s_setprio(0);
    if (j == jmax - 1) {                   // diagonal-tile causal mask
      int qrow = w * 16 + q;               // key-local: n*16+g*4+i > w*16+q
      #pragma unroll
      for (int n = 0; n < 8; n++)
        #pragma unroll
        for (int i = 0; i < 4; i++)
          if (n * 16 + g * 4 + i > qrow) s[n][i] = -1e30f;
    }
    // in-register softmax: one q-row per lane (+2 shfl across g-groups)
    float mt = -1e30f;
    #pragma unroll
    for (int n = 0; n < 8; n++)
      mt = fmaxf(mt, fmaxf(fmaxf(s[n][0], s[n][1]), fmaxf(s[n][2], s[n][3])));
    mt = fmaxf(mt, __shfl_xor(mt, 16));
    mt = fmaxf(mt, __shfl_xor(mt, 32));
    if (__any(mt > mr + 8.f)) {            // defer-max: skip rescale when growth < 2^8
      float mnew = fmaxf(mr, mt);
      float sc = exp2f(mr - mnew);
      mr = mnew;
      lr *= sc;
      #pragma unroll
      for (int t = 0; t < 4; t++) acc[t] *= sc;
    }
    float ps = 0.f;
    U8 pa[4];                              // pa[kt] covers keys kt*32..kt*32+31
    #pragma unroll
    for (int kt = 0; kt < 4; kt++) {
      float p0[4], p1[4];
      #pragma unroll
      for (int i = 0; i < 4; i++) {
        p0[i] = exp2f(s[2 * kt][i] - mr);
        p1[i] = exp2f(s[2 * kt + 1][i] - mr);
        ps += p0[i] + p1[i];
      }
      pa[kt].u[0] = cvtpk(p0[0], p0[1]);
      pa[kt].u[1] = cvtpk(p0[2], p0[3]);
      pa[kt].u[2] = cvtpk(p1[0], p1[1]);
      pa[kt].u[3] = cvtpk(p1[2], p1[3]);
    }
    ps += __shfl_xor(ps, 16);
    ps += __shfl_xor(ps, 32);
    lr += ps;
    // PV: O^T[d][q] += V^T[d][k'] P^T[k'][q]; kt half = kt>>1, sub-chunk = kt&1
    __builtin_amdgcn_s_setprio(1);
    #pragma unroll
    for (int t = 0; t < 4; t++) {
      #pragma unroll
      for (int kt = 0; kt < 4; kt++) {
        const char* vrh = lVc + (kt >> 1) * 8192 + (t * 16 + q) * 128 + (g & 1) * 8;
        int ktl = kt & 1;
        u32x2 lo = *(const u32x2*)(vrh + (((ktl * 4 + (g >> 1)) ^ (q & 7)) * 16));
        u32x2 hi = *(const u32x2*)(vrh + (((ktl * 4 + 2 + (g >> 1)) ^ (q & 7)) * 16));
        U8 af;
        af.u[0] = lo[0]; af.u[1] = lo[1]; af.u[2] = hi[0]; af.u[3] = hi[1];
        acc[t] = mfma16(af.v, pa[kt].v, acc[t]);
      }
    }
    __builtin_amdgcn_s_setprio(0);
    __syncthreads();                       // drains prefetch; publishes buf cur^1
    cur ^= 1;
  }
  // epilogue: lane owns q-row (qrow0+q), cols d = t*16+g*4+{0..3} -> f32x4
  {
    float inv = 1.f / lr;
    size_t base = ((size_t)b * T_ + qrow0 + q) * D_ + h * 64 + g * 4;
    #pragma unroll
    for (int t = 0; t < 4; t++) {
      f32x4 r = *(const f32x4*)(xv + base + t * 16);
      f32x4 o;
      #pragma unroll
      for (int i = 0; i < 4; i++) o[i] = r[i] + acc[t][i] * inv;
      *(f32x4*)(X + base + t * 16) = o;
    }
  }
}

// ------------------------------- launch -------------------------------
extern "C" void kernel_launch(void* const* d_in, const int* in_sizes, int n_in,
                              void* d_out, int out_size, void* d_ws, size_t ws_size,
                              hipStream_t stream) {
  const int*   x_type   = (const int*)d_in[0];
  const float* x_value  = (const float*)d_in[1];
  const float* seq      = (const float*)d_in[2];
  const float* W_attn   = (const float*)d_in[3];
  const float* type_emb = (const float*)d_in[4];
  const float* ln1_g    = (const float*)d_in[5];
  const float* ln1_b    = (const float*)d_in[6];
  const float* ln2_g    = (const float*)d_in[7];
  const float* ln2_b    = (const float*)d_in[8];
  const float* W1       = (const float*)d_in[9];
  const float* b1       = (const float*)d_in[10];
  const float* W2       = (const float*)d_in[11];
  const float* b2       = (const float*)d_in[12];
  float* out = (float*)d_out;
  char* ws = (char*)d_ws;

  // workspace layout — total ~38.5 MiB
  u16*   WtA  = (u16*)(ws + 0);             // 1536x512 bf16  1.5 MiB
  u16*   W1i  = (u16*)(ws + 1572864);       // 2048x512 bf16 interleaved a/gate  2 MiB
  u16*   W2t  = (u16*)(ws + 3670016);       // 512x1024 bf16  1 MiB
  float* rqc  = (float*)(ws + 4718592);     // 4 rope tables, 512 KiB each
  float* rqs  = (float*)(ws + 5242880);
  float* rkc  = (float*)(ws + 5767168);
  float* rks  = (float*)(ws + 6291456);
  u16*   hbuf = (u16*)(ws + 6815744);       // 8192x512 bf16 (h, then h2)  8 MiB
  u16*   qTb  = (u16*)(ws + 15204352);      // (B,H,T,64) bf16  8 MiB
  u16*   kTb  = (u16*)(ws + 23592960);      // 8 MiB
  u16*   vTb  = (u16*)(ws + 31981568);      // (B,H,64,T) bf16  8 MiB
  u16*   ff1a = (u16*)(ws + 15204352);      // 8192x1024 bf16 16 MiB, aliases qT+kT (dead post-attn)

  prep_kernel<<<1088, 256, 0, stream>>>(W_attn, W1, W2, seq, WtA, W1i, W2t,
                                        rqc, rqs, rkc, rks);
  ln_kernel<<<B_ * T_ / 4, 256, 0, stream>>>(x_value, ln1_g, ln1_b, hbuf);
  gemm_qkv<<<768, 256, 0, stream>>>(hbuf, WtA, x_type, type_emb,
                                    rqc, rqs, rkc, rks, qTb, kTb, vTb);
  attn_kernel<<<512, 512, 0, stream>>>(qTb, kTb, vTb, x_value, out);
  ln_kernel<<<B_ * T_ / 4, 256, 0, stream>>>(out, ln2_g, ln2_b, hbuf);
  gemm_ff1<<<512, 512, 0, stream>>>(hbuf, W1i, b1, ff1a);
  gemm_ff2<<<256, 512, 0, stream>>>(ff1a, W2t, b2, out);
}

// Round 14
// 125.298 us; speedup vs baseline: 1.1196x; 1.0781x over previous
//
#include <hip/hip_runtime.h>
#include <stdint.h>
#include <math.h>

typedef unsigned short u16;
typedef unsigned int u32;
typedef __attribute__((ext_vector_type(8))) short bf16x8;   // 8 bf16 (4 VGPRs) MFMA A/B frag
typedef __attribute__((ext_vector_type(4))) float f32x4;
typedef __attribute__((ext_vector_type(2))) float f32x2;
typedef __attribute__((ext_vector_type(2))) u16 u16x2;
typedef __attribute__((ext_vector_type(8))) u16 u16x8;
typedef __attribute__((ext_vector_type(2))) u32 u32x2;

#define B_ 8
#define T_ 1024
#define D_ 512
#define H_ 8
#define TP1 1025
// q scale: 1/sqrt(64) * log2(e)  (softmax runs in exp2 domain)
#define QSCALE 0.1803368801111204f

__device__ __forceinline__ u16 f2b(float f) {           // f32 -> bf16 RNE
  union { float f; u32 u; } v; v.f = f;
  return (u16)((v.u + 0x7fffu + ((v.u >> 16) & 1u)) >> 16);
}
__device__ __forceinline__ void gld16(const void* g, void* l) {
  // async global->LDS, 16B/lane; LDS dest = wave-uniform base + lane*16
  __builtin_amdgcn_global_load_lds((const __attribute__((address_space(1))) u32*)g,
                                   (__attribute__((address_space(3))) u32*)l, 16, 0, 0);
}
__device__ __forceinline__ f32x4 mfma16(bf16x8 a, bf16x8 b, f32x4 c) {
  return __builtin_amdgcn_mfma_f32_16x16x32_bf16(a, b, c, 0, 0, 0);
}
__device__ __forceinline__ u32 cvtpk(float lo, float hi) {   // 2xf32 -> packed bf16x2 (RNE)
  u32 r;
  asm("v_cvt_pk_bf16_f32 %0, %1, %2" : "=v"(r) : "v"(lo), "v"(hi));
  return r;
}
union U8 { u32 u[4]; bf16x8 v; };

// counted-vmcnt waits: wait for the OLDEST stage only, keep the rest in flight
#define WAITV(N) asm volatile("s_waitcnt vmcnt(" #N ")" ::: "memory")

// ---------------- fused prep: tiled (coalesced) weight transposes + rope tables ----------------
__global__ __launch_bounds__(256) void prep_kernel(const float* __restrict__ W_attn,
    const float* __restrict__ W1, const float* __restrict__ W2,
    const float* __restrict__ seq,
    u16* __restrict__ WtA, u16* __restrict__ W1i, u16* __restrict__ W2t,
    float* __restrict__ cq, float* __restrict__ sq_,
    float* __restrict__ ck, float* __restrict__ sk) {
  int bid = blockIdx.x, tid = threadIdx.x;
  if (bid >= 576) {                        // rope: B*T*16 elements
    int i = (bid - 576) * 256 + tid;
    int p = i & 15, bt = i >> 4, b = bt >> 10, t = bt & 1023;
    float inv = expf(-(float)p * 0.5756462732485115f);   // 10000^(-p/16)
    float aq = seq[b * TP1 + t] * inv;
    float ak = seq[b * TP1 + t + 1] * inv;
    cq[i] = cosf(aq); sq_[i] = sinf(aq);
    ck[i] = cosf(ak); sk[i] = sinf(ak);
    return;
  }
  __shared__ u16 lt[64][65];
  const float* src; u16* dst; int ld, Kd, k0, r0; bool ilv = false;
  if (bid < 192) {            // WtA: 8 k-tiles x 24 n-tiles
    src = W_attn; dst = WtA; ld = 1536; Kd = 512;
    k0 = (bid & 7) * 64; r0 = (bid >> 3) * 64;
  } else if (bid < 448) {     // W1i: 8 k-tiles x 32 r-tiles, interleaved
    int t = bid - 192;
    src = W1; dst = W1i; ld = 2048; Kd = 512; ilv = true;
    k0 = (t & 7) * 64; r0 = (t >> 3) * 64;
  } else {                    // W2t: 16 k-tiles x 8 n-tiles
    int t = bid - 448;
    src = W2; dst = W2t; ld = 512; Kd = 1024;
    k0 = (t & 15) * 64; r0 = (t >> 4) * 64;
  }
  int nl = tid & 63;
  int scol, rloc;
  if (ilv) {
    if (nl < 32) { scol = (r0 >> 1) + nl;          rloc = ((nl >> 4) << 5) + (nl & 15); }
    else         { scol = 1024 + (r0 >> 1) + (nl - 32); rloc = (((nl - 32) >> 4) << 5) + 16 + (nl & 15); }
  } else { scol = r0 + nl; rloc = nl; }
  #pragma unroll
  for (int it = 0; it < 16; it++) {
    int kl = (tid >> 6) * 16 + it;
    lt[rloc][kl] = f2b(src[(size_t)(k0 + kl) * ld + scol]);
  }
  __syncthreads();
  #pragma unroll
  for (int it = 0; it < 16; it++) {
    int rl = (tid >> 6) * 16 + it;
    dst[(size_t)(r0 + rl) * Kd + k0 + nl] = lt[rl][nl];
  }
}

// ---------------- LayerNorm: one WAVE per row, no LDS, no barriers ----------------
__global__ __launch_bounds__(256) void ln_kernel(const float* __restrict__ x,
    const float* __restrict__ g, const float* __restrict__ bta, u16* __restrict__ out) {
  int row = blockIdx.x * 4 + (threadIdx.x >> 6);    // 8192 rows, 4 rows/block
  int lane = threadIdx.x & 63;
  const float* xr = x + (size_t)row * D_ + lane * 8;
  f32x4 v0 = *(const f32x4*)xr;
  f32x4 v1 = *(const f32x4*)(xr + 4);
  float s = 0.f, sq = 0.f;
  #pragma unroll
  for (int j = 0; j < 4; j++) { s += v0[j] + v1[j]; sq += v0[j] * v0[j] + v1[j] * v1[j]; }
  #pragma unroll
  for (int m = 1; m < 64; m <<= 1) { s += __shfl_xor(s, m); sq += __shfl_xor(sq, m); }
  float mean = s * (1.f / D_);
  float var = sq * (1.f / D_) - mean * mean;
  float rstd = rsqrtf(var + 1e-5f);
  f32x4 g0 = *(const f32x4*)(g + lane * 8);
  f32x4 g1 = *(const f32x4*)(g + lane * 8 + 4);
  f32x4 b0 = *(const f32x4*)(bta + lane * 8);
  f32x4 b1 = *(const f32x4*)(bta + lane * 8 + 4);
  u16x8 o;
  #pragma unroll
  for (int j = 0; j < 4; j++) {
    o[j]     = f2b((v0[j] - mean) * rstd * g0[j] + b0[j]);
    o[4 + j] = f2b((v1[j] - mean) * rstd * g1[j] + b1[j]);
  }
  *(u16x8*)(out + (size_t)row * D_ + lane * 8) = o;
}

// ---------------- QKV GEMM: 128x128, 4 waves, 3-deep counted pipeline ----------------
// Fused epilogue: type-emb + RoPE + scale + head layout; V region stored via
// LDS transpose (staging LDS reused, dead after K-loop) for coalesced u16x8 stores.
__global__ __launch_bounds__(256) void gemm_qkv(const u16* __restrict__ A,
    const u16* __restrict__ Bt,
    const int* __restrict__ x_type, const float* __restrict__ type_emb,
    const float* __restrict__ rqc, const float* __restrict__ rqs,
    const float* __restrict__ rkc, const float* __restrict__ rks,
    u16* __restrict__ qT, u16* __restrict__ kT, u16* __restrict__ vT) {
  __shared__ u16 lsmem[6 * 4096];          // 48KB: lA[3][4096] | lB[3][4096]
  u16* lA = lsmem;
  u16* lB = lsmem + 3 * 4096;
  const int K = 512, NK = 16;
  const int tid = threadIdx.x, lane = tid & 63, w = tid >> 6;
  const int wm = w >> 1, wn = w & 1;
  int swz = (blockIdx.x & 7) * 96 + (blockIdx.x >> 3);
  int byy = swz / 12, bxx = swz - byy * 12;
  const size_t bm = (size_t)byy * 128;
  const size_t bn = (size_t)bxx * 128;

  const int r0 = tid >> 2;
  const int cs = ((tid & 3) ^ ((r0 >> 1) & 3)) * 8;
  const u16* a0 = A + (bm + r0) * K + cs;
  const u16* a1 = A + (bm + 64 + r0) * K + cs;
  const u16* b0 = Bt + (bn + r0) * K + cs;
  const u16* b1p = Bt + (bn + 64 + r0) * K + cs;

  int aoff[4], boff[4];
  #pragma unroll
  for (int i = 0; i < 4; i++) {
    int ra = wm * 64 + i * 16 + (lane & 15);
    aoff[i] = ra * 64 + (((lane >> 4) ^ ((ra >> 1) & 3)) * 16);
    int rb = wn * 64 + i * 16 + (lane & 15);
    boff[i] = rb * 64 + (((lane >> 4) ^ ((rb >> 1) & 3)) * 16);
  }

  auto stage = [&](int j, int buf) {      // 4 loads
    char* ad = (char*)lA + buf * 8192 + w * 1024;
    char* bd = (char*)lB + buf * 8192 + w * 1024;
    gld16(a0 + j * 32, ad);
    gld16(a1 + j * 32, ad + 4096);
    gld16(b0 + j * 32, bd);
    gld16(b1p + j * 32, bd + 4096);
  };
  f32x4 acc[4][4] = {};
  auto compute = [&](int buf) {
    const char* lAc = (const char*)lA + buf * 8192;
    const char* lBc = (const char*)lB + buf * 8192;
    bf16x8 af[4], bf[4];
    #pragma unroll
    for (int i = 0; i < 4; i++) af[i] = *(const bf16x8*)(lAc + aoff[i]);
    #pragma unroll
    for (int n = 0; n < 4; n++) bf[n] = *(const bf16x8*)(lBc + boff[n]);
    __builtin_amdgcn_s_setprio(1);
    #pragma unroll
    for (int i = 0; i < 4; i++)
      #pragma unroll
      for (int n = 0; n < 4; n++)
        acc[i][n] = mfma16(af[i], bf[n], acc[i][n]);
    __builtin_amdgcn_s_setprio(0);
  };

  stage(0, 0);
  stage(1, 1);
  int cur = 0;
  for (int j = 0; j < NK - 1; j++) {
    WAITV(4);                              // oldest stage landed; next stays in flight
    __builtin_amdgcn_s_barrier();
    if (j + 2 < NK) { int nb = cur + 2; if (nb >= 3) nb -= 3; stage(j + 2, nb); }
    compute(cur);
    cur = (cur + 1 == 3) ? 0 : cur + 1;
  }
  WAITV(0);
  __builtin_amdgcn_s_barrier();
  compute(cur);

  // fused epilogue. block-uniform region: 0=q (cols 0..511), 1=k, 2=v
  const int region = (int)(bn >> 9);
  if (region < 2) {
    #pragma unroll
    for (int i = 0; i < 4; i++) {
      #pragma unroll
      for (int jj = 0; jj < 4; jj++) {
        int row = (int)bm + wm * 64 + i * 16 + (lane >> 4) * 4 + jj;   // bt index
        int b = row >> 10, t = row & 1023;
        if (region == 0) {
          int ty = x_type[b * TP1 + t];
          #pragma unroll
          for (int n = 0; n < 4; n++) {
            int cloc = (int)bn + wn * 64 + n * 16 + (lane & 15);       // 0..511
            int h = cloc >> 6, hd = cloc & 63;
            float v = acc[i][n][jj] + type_emb[(size_t)ty * 1024 + cloc];
            float vp = __shfl_xor(v, 1);
            if (hd < 32) {
              int p = hd >> 1;
              float c = rqc[row * 16 + p], s = rqs[row * 16 + p];
              v = (hd & 1) ? (v * c + vp * s) : (v * c - vp * s);
            }
            qT[((size_t)(b * 8 + h) * T_ + t) * 64 + hd] = f2b(v * QSCALE);
          }
        } else {
          int ty = x_type[b * TP1 + t + 1];
          #pragma unroll
          for (int n = 0; n < 4; n++) {
            int cloc = (int)bn - 512 + wn * 64 + n * 16 + (lane & 15); // 0..511
            int h = cloc >> 6, hd = cloc & 63;
            float v = acc[i][n][jj] + type_emb[(size_t)ty * 1024 + 512 + cloc];
            float vp = __shfl_xor(v, 1);
            if (hd < 32) {
              int p = hd >> 1;
              float c = rkc[row * 16 + p], s = rks[row * 16 + p];
              v = (hd & 1) ? (v * c + vp * s) : (v * c - vp * s);
            }
            kT[((size_t)(b * 8 + h) * T_ + t) * 64 + hd] = f2b(v);
          }
        }
      }
    }
  } else {
    // V region: transpose through (dead) staging LDS for coalesced u16x8 stores.
    __syncthreads();                       // all waves done reading lA/lB
    u16 (*tbuf)[136] = (u16(*)[136])lsmem; // 128 x 136 u16 = 34816B <= 48KB
    #pragma unroll
    for (int i = 0; i < 4; i++) {
      #pragma unroll
      for (int n = 0; n < 4; n++) {
        int cl = wn * 64 + n * 16 + (lane & 15);       // v-col local 0..127
        #pragma unroll
        for (int jj = 0; jj < 4; jj++) {
          int r = wm * 64 + i * 16 + (lane >> 4) * 4 + jj;   // t local 0..127
          tbuf[cl][r] = f2b(acc[i][n][jj]);
        }
      }
    }
    __syncthreads();
    const int bb = (int)(bm >> 10);
    const int t0 = (int)(bm & 1023);
    const int h0 = ((int)bn - 1024) >> 6;              // first head (of 2) in this block
    const size_t rbase = (size_t)(bb * 8 + h0) * 64;   // vT row of cl=0
    #pragma unroll
    for (int p = 0; p < 8; p++) {
      int rl = p * 16 + (tid >> 4);                    // 0..127 (hd-major local)
      int c8 = (tid & 15) * 8;                         // t chunk
      u16x8 o = *(const u16x8*)&tbuf[rl][c8];
      *(u16x8*)(vT + (rbase + rl) * T_ + t0 + c8) = o;
    }
  }
}

// ---------------- FF1 GEMM: BM=256 x BN=128, BK=32, 512 thr / 8 waves, 2-phase ----------------
__global__ __launch_bounds__(512) void gemm_ff1(const u16* __restrict__ A,
    const u16* __restrict__ Bt, const float* __restrict__ b1,
    u16* __restrict__ outp) {
  __shared__ u16 lA[2][8192];              // 256 rows x 32 cols per buf (16KB)
  __shared__ u16 lB[2][4096];              // 128 rows x 32 cols per buf (8KB)
  const int K = 512;
  const int tid = threadIdx.x, lane = tid & 63, w = tid >> 6;   // 8 waves
  const int wm = w >> 2, wn = w & 3;
  int swz = (blockIdx.x & 7) * 64 + (blockIdx.x >> 3);          // 512 blocks
  int byy = swz >> 4, bxx = swz & 15;                           // 32 x 16
  const size_t bm = (size_t)byy * 256;
  const size_t bn = (size_t)bxx * 128;

  const int r0 = tid >> 2;                                      // 0..127
  const int cs = ((tid & 3) ^ ((r0 >> 1) & 3)) * 8;
  const u16* a0 = A + (bm + r0) * K + cs;
  const u16* a1 = A + (bm + 128 + r0) * K + cs;
  const u16* b0 = Bt + (bn + r0) * K + cs;

  int aoff[8], boff[2];
  #pragma unroll
  for (int i = 0; i < 8; i++) {
    int ra = wm * 128 + i * 16 + (lane & 15);
    aoff[i] = ra * 64 + (((lane >> 4) ^ ((ra >> 1) & 3)) * 16);
  }
  #pragma unroll
  for (int n = 0; n < 2; n++) {
    int rb = wn * 32 + n * 16 + (lane & 15);
    boff[n] = rb * 64 + (((lane >> 4) ^ ((rb >> 1) & 3)) * 16);
  }

  auto stage = [&](int k0, int buf) {      // 3 gld16 calls (8KB each)
    char* ad = (char*)lA + buf * 16384 + w * 1024;
    char* bd = (char*)lB + buf * 8192 + w * 1024;
    gld16(a0 + k0, ad);                    // A rows 0..127
    gld16(a1 + k0, ad + 8192);             // A rows 128..255
    gld16(b0 + k0, bd);                    // B rows 0..127
  };

  f32x4 acc[8][2] = {};
  stage(0, 0);
  __syncthreads();
  int cur = 0;
  for (int k0 = 0; k0 < K; k0 += 32) {
    if (k0 + 32 < K) stage(k0 + 32, cur ^ 1);
    const char* lAc = (const char*)lA + cur * 16384;
    const char* lBc = (const char*)lB + cur * 8192;
    bf16x8 bf[2];
    #pragma unroll
    for (int n = 0; n < 2; n++) bf[n] = *(const bf16x8*)(lBc + boff[n]);
    __builtin_amdgcn_s_setprio(1);
    #pragma unroll
    for (int i = 0; i < 8; i++) {
      bf16x8 af = *(const bf16x8*)(lAc + aoff[i]);
      acc[i][0] = mfma16(af, bf[0], acc[i][0]);
      acc[i][1] = mfma16(af, bf[1], acc[i][1]);
    }
    __builtin_amdgcn_s_setprio(0);
    __syncthreads();
    cur ^= 1;
  }
  // epilogue: real col c = bn/2 + wn*16 + (lane&15); a = acc[i][0], g = acc[i][1]
  {
    int c = ((int)bn >> 1) + wn * 16 + (lane & 15);
    float bav = b1[c], bgv = b1[1024 + c];
    #pragma unroll
    for (int i = 0; i < 8; i++) {
      #pragma unroll
      for (int jj = 0; jj < 4; jj++) {
        int row = (int)bm + wm * 128 + i * 16 + (lane >> 4) * 4 + jj;
        float av = acc[i][0][jj] + bav;
        float gv = acc[i][1][jj] + bgv;
        float sg = gv / (1.f + expf(-gv));
        outp[(size_t)row * 1024 + c] = f2b(sg * av);
      }
    }
  }
}

// ---------------- FF2 GEMM, 512 thr / 8 waves, 3-deep counted pipeline ----------------
__global__ __launch_bounds__(512) void gemm_ff2(const u16* __restrict__ A,
    const u16* __restrict__ Bt, const float* __restrict__ bias,
    float* __restrict__ C) {
  __shared__ u16 lA[3][4096];
  __shared__ u16 lB[3][4096];
  const int K = 1024, N = 512, NK = 32;
  const int tid = threadIdx.x, lane = tid & 63, w = tid >> 6;   // w 0..7
  const int wm = w >> 2, wn = w & 3;                            // 2x4 waves: 64x32 each
  int swz = (blockIdx.x & 7) * 32 + (blockIdx.x >> 3);          // 256 blocks
  int byy = swz >> 2, bxx = swz & 3;
  const size_t bm = (size_t)byy * 128;
  const size_t bn = (size_t)bxx * 128;

  const int r0 = tid >> 2;                                      // 0..127
  const int cs = ((tid & 3) ^ ((r0 >> 1) & 3)) * 8;
  const u16* a0 = A + (bm + r0) * K + cs;
  const u16* b0 = Bt + (bn + r0) * K + cs;

  int aoff[4], boff[2];
  #pragma unroll
  for (int i = 0; i < 4; i++) {
    int ra = wm * 64 + i * 16 + (lane & 15);
    aoff[i] = ra * 64 + (((lane >> 4) ^ ((ra >> 1) & 3)) * 16);
  }
  #pragma unroll
  for (int n = 0; n < 2; n++) {
    int rb = wn * 32 + n * 16 + (lane & 15);
    boff[n] = rb * 64 + (((lane >> 4) ^ ((rb >> 1) & 3)) * 16);
  }

  auto stage = [&](int j, int buf) {      // 2 loads
    gld16(a0 + j * 32, (char*)lA + buf * 8192 + w * 1024);
    gld16(b0 + j * 32, (char*)lB + buf * 8192 + w * 1024);
  };
  f32x4 acc[4][2] = {};
  auto compute = [&](int buf) {
    const char* lAc = (const char*)lA + buf * 8192;
    const char* lBc = (const char*)lB + buf * 8192;
    bf16x8 af[4], bf[2];
    #pragma unroll
    for (int i = 0; i < 4; i++) af[i] = *(const bf16x8*)(lAc + aoff[i]);
    #pragma unroll
    for (int n = 0; n < 2; n++) bf[n] = *(const bf16x8*)(lBc + boff[n]);
    __builtin_amdgcn_s_setprio(1);
    #pragma unroll
    for (int i = 0; i < 4; i++)
      #pragma unroll
      for (int n = 0; n < 2; n++)
        acc[i][n] = mfma16(af[i], bf[n], acc[i][n]);
    __builtin_amdgcn_s_setprio(0);
  };

  stage(0, 0);
  stage(1, 1);
  int cur = 0;
  for (int j = 0; j < NK - 1; j++) {
    WAITV(2);
    __builtin_amdgcn_s_barrier();
    if (j + 2 < NK) { int nb = cur + 2; if (nb >= 3) nb -= 3; stage(j + 2, nb); }
    compute(cur);
    cur = (cur + 1 == 3) ? 0 : cur + 1;
  }
  WAITV(0);
  __builtin_amdgcn_s_barrier();
  compute(cur);

  #pragma unroll
  for (int i = 0; i < 4; i++) {
    size_t mrow = bm + wm * 64 + i * 16 + (lane >> 4) * 4;
    #pragma unroll
    for (int n = 0; n < 2; n++) {
      size_t col = bn + wn * 32 + n * 16 + (lane & 15);
      float bv = bias[col];
      #pragma unroll
      for (int jj = 0; jj < 4; jj++) {
        size_t idx = (mrow + jj) * (size_t)N + col;
        C[idx] = acc[i][n][jj] + bv + C[idx];   // in-place residual
      }
    }
  }
}

// ---------------- causal flash attention + residual: out = x_value + attn ----------------
// 8 waves / 512 thr / 128 q-rows, 2-phase LDS dbuf with KVBLK=128 (two proven 8KB
// sub-tiles per buffer): jmax = qp+1 barrier-locked iterations (max 8).
__global__ __launch_bounds__(512, 4) void attn_kernel(const u16* __restrict__ qT,
    const u16* __restrict__ kT, const u16* __restrict__ vT,
    const float* __restrict__ xv, float* __restrict__ X) {
  int s0 = (blockIdx.x & 7) * 64 + (blockIdx.x >> 3);   // 512 blocks, 8 bh per XCD
  const int bh = ((blockIdx.x & 7) << 3) + (s0 & 7);    // 8 bh per XCD
  const int qp = 7 - ((s0 >> 3) & 7);                   // true LPT: qp=7 of all bh first
  const int b = bh >> 3, h = bh & 7;
  const int tid = threadIdx.x, lane = tid & 63, w = tid >> 6;   // 8 waves
  const int q = lane & 15, g = lane >> 4;
  __shared__ u16 lK[2][8192];              // [buf][half0 8KB | half1 8KB]
  __shared__ u16 lV[2][8192];

  const int qrow0 = qp * 128 + w * 16;     // this wave's 16-row q-strip
  bf16x8 qf[2];
  {
    const u16* qp_ = qT + ((size_t)bh * T_ + qrow0 + q) * 64 + g * 8;
    qf[0] = *(const bf16x8*)qp_;
    qf[1] = *(const bf16x8*)(qp_ + 32);
  }
  f32x4 acc[4] = {};
  float mr = -1e30f, lr = 0.f;

  const int sr = tid >> 3;                 // 0..63
  const int scs = ((tid & 7) ^ (sr & 7)) * 8;
  const u16* kb = kT + ((size_t)bh * T_ + sr) * 64 + scs;
  const u16* vb = vT + ((size_t)bh * 64 + sr) * T_ + scs;

  auto stage = [&](int j, int buf) {       // K rows [j*128,+128), V cols [j*128,+128)
    char* kd = (char*)lK + buf * 16384 + w * 1024;
    char* vd = (char*)lV + buf * 16384 + w * 1024;
    gld16(kb + (size_t)j * 8192, kd);              // K half0 (rows +0..63)
    gld16(kb + (size_t)j * 8192 + 4096, kd + 8192);// K half1 (rows +64..127)
    gld16(vb + j * 128, vd);                       // V half0 (cols +0..63)
    gld16(vb + j * 128 + 64, vd + 8192);           // V half1 (cols +64..127)
  };

  const int jmax = qp + 1;
  stage(0, 0);
  __syncthreads();
  int cur = 0;
  for (int j = 0; j < jmax; j++) {
    if (j + 1 < jmax) stage(j + 1, cur ^ 1);   // prefetch next 128-tile under compute
    const char* lKc = (const char*)lK + cur * 16384;
    const char* lVc = (const char*)lV + cur * 16384;

    // QK^T swapped: s[n][i] = S[key = j*128 + n*16+g*4+i][qrow0+q]
    f32x4 s[8] = {};
    __builtin_amdgcn_s_setprio(1);
    #pragma unroll
    for (int ka = 0; ka < 2; ka++) {
      #pragma unroll
      for (int n = 0; n < 8; n++) {
        bf16x8 kf = *(const bf16x8*)(lKc + (n >> 2) * 8192 + ((n & 3) * 16 + q) * 128 +
                                     (((ka * 4 + g) ^ (q & 7)) * 16));
        s[n] = mfma16(kf, qf[ka], s[n]);
      }
    }
    __builtin_amdgcn_s_setprio(0);
    if (j == jmax - 1) {                   // diagonal-tile causal mask
      int qrow = w * 16 + q;               // key-local: n*16+g*4+i > w*16+q
      #pragma unroll
      for (int n = 0; n < 8; n++)
        #pragma unroll
        for (int i = 0; i < 4; i++)
          if (n * 16 + g * 4 + i > qrow) s[n][i] = -1e30f;
    }
    // in-register softmax: one q-row per lane (+2 shfl across g-groups)
    float mt = -1e30f;
    #pragma unroll
    for (int n = 0; n < 8; n++)
      mt = fmaxf(mt, fmaxf(fmaxf(s[n][0], s[n][1]), fmaxf(s[n][2], s[n][3])));
    mt = fmaxf(mt, __shfl_xor(mt, 16));
    mt = fmaxf(mt, __shfl_xor(mt, 32));
    if (__any(mt > mr + 8.f)) {            // defer-max: skip rescale when growth < 2^8
      float mnew = fmaxf(mr, mt);
      float sc = exp2f(mr - mnew);
      mr = mnew;
      lr *= sc;
      #pragma unroll
      for (int t = 0; t < 4; t++) acc[t] *= sc;
    }
    float ps = 0.f;
    U8 pa[4];                              // pa[kt] covers keys kt*32..kt*32+31
    #pragma unroll
    for (int kt = 0; kt < 4; kt++) {
      float p0[4], p1[4];
      #pragma unroll
      for (int i = 0; i < 4; i++) {
        p0[i] = exp2f(s[2 * kt][i] - mr);
        p1[i] = exp2f(s[2 * kt + 1][i] - mr);
        ps += p0[i] + p1[i];
      }
      pa[kt].u[0] = cvtpk(p0[0], p0[1]);
      pa[kt].u[1] = cvtpk(p0[2], p0[3]);
      pa[kt].u[2] = cvtpk(p1[0], p1[1]);
      pa[kt].u[3] = cvtpk(p1[2], p1[3]);
    }
    ps += __shfl_xor(ps, 16);
    ps += __shfl_xor(ps, 32);
    lr += ps;
    // PV: O^T[d][q] += V^T[d][k'] P^T[k'][q]; kt half = kt>>1, sub-chunk = kt&1
    __builtin_amdgcn_s_setprio(1);
    #pragma unroll
    for (int t = 0; t < 4; t++) {
      #pragma unroll
      for (int kt = 0; kt < 4; kt++) {
        const char* vrh = lVc + (kt >> 1) * 8192 + (t * 16 + q) * 128 + (g & 1) * 8;
        int ktl = kt & 1;
        u32x2 lo = *(const u32x2*)(vrh + (((ktl * 4 + (g >> 1)) ^ (q & 7)) * 16));
        u32x2 hi = *(const u32x2*)(vrh + (((ktl * 4 + 2 + (g >> 1)) ^ (q & 7)) * 16));
        U8 af;
        af.u[0] = lo[0]; af.u[1] = lo[1]; af.u[2] = hi[0]; af.u[3] = hi[1];
        acc[t] = mfma16(af.v, pa[kt].v, acc[t]);
      }
    }
    __builtin_amdgcn_s_setprio(0);
    __syncthreads();                       // drains prefetch; publishes buf cur^1
    cur ^= 1;
  }
  // epilogue: lane owns q-row (qrow0+q), cols d = t*16+g*4+{0..3} -> f32x4
  {
    float inv = 1.f / lr;
    size_t base = ((size_t)b * T_ + qrow0 + q) * D_ + h * 64 + g * 4;
    #pragma unroll
    for (int t = 0; t < 4; t++) {
      f32x4 r = *(const f32x4*)(xv + base + t * 16);
      f32x4 o;
      #pragma unroll
      for (int i = 0; i < 4; i++) o[i] = r[i] + acc[t][i] * inv;
      *(f32x4*)(X + base + t * 16) = o;
    }
  }
}

// ------------------------------- launch -------------------------------
extern "C" void kernel_launch(void* const* d_in, const int* in_sizes, int n_in,
                              void* d_out, int out_size, void* d_ws, size_t ws_size,
                              hipStream_t stream) {
  const int*   x_type   = (const int*)d_in[0];
  const float* x_value  = (const float*)d_in[1];
  const float* seq      = (const float*)d_in[2];
  const float* W_attn   = (const float*)d_in[3];
  const float* type_emb = (const float*)d_in[4];
  const float* ln1_g    = (const float*)d_in[5];
  const float* ln1_b    = (const float*)d_in[6];
  const float* ln2_g    = (const float*)d_in[7];
  const float* ln2_b    = (const float*)d_in[8];
  const float* W1       = (const float*)d_in[9];
  const float* b1       = (const float*)d_in[10];
  const float* W2       = (const float*)d_in[11];
  const float* b2       = (const float*)d_in[12];
  float* out = (float*)d_out;
  char* ws = (char*)d_ws;

  // workspace layout — total ~38.5 MiB
  u16*   WtA  = (u16*)(ws + 0);             // 1536x512 bf16  1.5 MiB
  u16*   W1i  = (u16*)(ws + 1572864);       // 2048x512 bf16 interleaved a/gate  2 MiB
  u16*   W2t  = (u16*)(ws + 3670016);       // 512x1024 bf16  1 MiB
  float* rqc  = (float*)(ws + 4718592);     // 4 rope tables, 512 KiB each
  float* rqs  = (float*)(ws + 5242880);
  float* rkc  = (float*)(ws + 5767168);
  float* rks  = (float*)(ws + 6291456);
  u16*   hbuf = (u16*)(ws + 6815744);       // 8192x512 bf16 (h, then h2)  8 MiB
  u16*   qTb  = (u16*)(ws + 15204352);      // (B,H,T,64) bf16  8 MiB
  u16*   kTb  = (u16*)(ws + 23592960);      // 8 MiB
  u16*   vTb  = (u16*)(ws + 31981568);      // (B,H,64,T) bf16  8 MiB
  u16*   ff1a = (u16*)(ws + 15204352);      // 8192x1024 bf16 16 MiB, aliases qT+kT (dead post-attn)

  prep_kernel<<<1088, 256, 0, stream>>>(W_attn, W1, W2, seq, WtA, W1i, W2t,
                                        rqc, rqs, rkc, rks);
  ln_kernel<<<B_ * T_ / 4, 256, 0, stream>>>(x_value, ln1_g, ln1_b, hbuf);
  gemm_qkv<<<768, 256, 0, stream>>>(hbuf, WtA, x_type, type_emb,
                                    rqc, rqs, rkc, rks, qTb, kTb, vTb);
  attn_kernel<<<512, 512, 0, stream>>>(qTb, kTb, vTb, x_value, out);
  ln_kernel<<<B_ * T_ / 4, 256, 0, stream>>>(out, ln2_g, ln2_b, hbuf);
  gemm_ff1<<<512, 512, 0, stream>>>(hbuf, W1i, b1, ff1a);
  gemm_ff2<<<256, 512, 0, stream>>>(ff1a, W2t, b2, out);
}

// Round 15
// 123.540 us; speedup vs baseline: 1.1355x; 1.0142x over previous
//
#include <hip/hip_runtime.h>
#include <stdint.h>
#include <math.h>

typedef unsigned short u16;
typedef unsigned int u32;
typedef __attribute__((ext_vector_type(8))) short bf16x8;   // 8 bf16 (4 VGPRs) MFMA A/B frag
typedef __attribute__((ext_vector_type(4))) float f32x4;
typedef __attribute__((ext_vector_type(2))) float f32x2;
typedef __attribute__((ext_vector_type(2))) u16 u16x2;
typedef __attribute__((ext_vector_type(8))) u16 u16x8;
typedef __attribute__((ext_vector_type(2))) u32 u32x2;

#define B_ 8
#define T_ 1024
#define D_ 512
#define H_ 8
#define TP1 1025
// q scale: 1/sqrt(64) * log2(e)  (softmax runs in exp2 domain)
#define QSCALE 0.1803368801111204f

__device__ __forceinline__ u16 f2b(float f) {           // f32 -> bf16 RNE
  union { float f; u32 u; } v; v.f = f;
  return (u16)((v.u + 0x7fffu + ((v.u >> 16) & 1u)) >> 16);
}
__device__ __forceinline__ void gld16(const void* g, void* l) {
  // async global->LDS, 16B/lane; LDS dest = wave-uniform base + lane*16
  __builtin_amdgcn_global_load_lds((const __attribute__((address_space(1))) u32*)g,
                                   (__attribute__((address_space(3))) u32*)l, 16, 0, 0);
}
__device__ __forceinline__ f32x4 mfma16(bf16x8 a, bf16x8 b, f32x4 c) {
  return __builtin_amdgcn_mfma_f32_16x16x32_bf16(a, b, c, 0, 0, 0);
}
__device__ __forceinline__ u32 cvtpk(float lo, float hi) {   // 2xf32 -> packed bf16x2 (RNE)
  u32 r;
  asm("v_cvt_pk_bf16_f32 %0, %1, %2" : "=v"(r) : "v"(lo), "v"(hi));
  return r;
}
union U8 { u32 u[4]; bf16x8 v; };

// counted-vmcnt waits: wait for the OLDEST stage only, keep the rest in flight
#define WAITV(N) asm volatile("s_waitcnt vmcnt(" #N ")" ::: "memory")

// ---------------- fused prep: tiled (coalesced) weight transposes + rope tables ----------------
__global__ __launch_bounds__(256) void prep_kernel(const float* __restrict__ W_attn,
    const float* __restrict__ W1, const float* __restrict__ W2,
    const float* __restrict__ seq,
    u16* __restrict__ WtA, u16* __restrict__ W1i, u16* __restrict__ W2t,
    float* __restrict__ cq, float* __restrict__ sq_,
    float* __restrict__ ck, float* __restrict__ sk) {
  int bid = blockIdx.x, tid = threadIdx.x;
  if (bid >= 576) {                        // rope: B*T*16 elements
    int i = (bid - 576) * 256 + tid;
    int p = i & 15, bt = i >> 4, b = bt >> 10, t = bt & 1023;
    float inv = expf(-(float)p * 0.5756462732485115f);   // 10000^(-p/16)
    float aq = seq[b * TP1 + t] * inv;
    float ak = seq[b * TP1 + t + 1] * inv;
    cq[i] = cosf(aq); sq_[i] = sinf(aq);
    ck[i] = cosf(ak); sk[i] = sinf(ak);
    return;
  }
  __shared__ u16 lt[64][65];
  const float* src; u16* dst; int ld, Kd, k0, r0; bool ilv = false;
  if (bid < 192) {            // WtA: 8 k-tiles x 24 n-tiles
    src = W_attn; dst = WtA; ld = 1536; Kd = 512;
    k0 = (bid & 7) * 64; r0 = (bid >> 3) * 64;
  } else if (bid < 448) {     // W1i: 8 k-tiles x 32 r-tiles, interleaved
    int t = bid - 192;
    src = W1; dst = W1i; ld = 2048; Kd = 512; ilv = true;
    k0 = (t & 7) * 64; r0 = (t >> 3) * 64;
  } else {                    // W2t: 16 k-tiles x 8 n-tiles
    int t = bid - 448;
    src = W2; dst = W2t; ld = 512; Kd = 1024;
    k0 = (t & 15) * 64; r0 = (t >> 4) * 64;
  }
  int nl = tid & 63;
  int scol, rloc;
  if (ilv) {
    if (nl < 32) { scol = (r0 >> 1) + nl;          rloc = ((nl >> 4) << 5) + (nl & 15); }
    else         { scol = 1024 + (r0 >> 1) + (nl - 32); rloc = (((nl - 32) >> 4) << 5) + 16 + (nl & 15); }
  } else { scol = r0 + nl; rloc = nl; }
  #pragma unroll
  for (int it = 0; it < 16; it++) {
    int kl = (tid >> 6) * 16 + it;
    lt[rloc][kl] = f2b(src[(size_t)(k0 + kl) * ld + scol]);
  }
  __syncthreads();
  #pragma unroll
  for (int it = 0; it < 16; it++) {
    int rl = (tid >> 6) * 16 + it;
    dst[(size_t)(r0 + rl) * Kd + k0 + nl] = lt[rl][nl];
  }
}

// ---------------- LayerNorm: one WAVE per row, no LDS, no barriers ----------------
__global__ __launch_bounds__(256) void ln_kernel(const float* __restrict__ x,
    const float* __restrict__ g, const float* __restrict__ bta, u16* __restrict__ out) {
  int row = blockIdx.x * 4 + (threadIdx.x >> 6);    // 8192 rows, 4 rows/block
  int lane = threadIdx.x & 63;
  const float* xr = x + (size_t)row * D_ + lane * 8;
  f32x4 v0 = *(const f32x4*)xr;
  f32x4 v1 = *(const f32x4*)(xr + 4);
  float s = 0.f, sq = 0.f;
  #pragma unroll
  for (int j = 0; j < 4; j++) { s += v0[j] + v1[j]; sq += v0[j] * v0[j] + v1[j] * v1[j]; }
  #pragma unroll
  for (int m = 1; m < 64; m <<= 1) { s += __shfl_xor(s, m); sq += __shfl_xor(sq, m); }
  float mean = s * (1.f / D_);
  float var = sq * (1.f / D_) - mean * mean;
  float rstd = rsqrtf(var + 1e-5f);
  f32x4 g0 = *(const f32x4*)(g + lane * 8);
  f32x4 g1 = *(const f32x4*)(g + lane * 8 + 4);
  f32x4 b0 = *(const f32x4*)(bta + lane * 8);
  f32x4 b1 = *(const f32x4*)(bta + lane * 8 + 4);
  u16x8 o;
  #pragma unroll
  for (int j = 0; j < 4; j++) {
    o[j]     = f2b((v0[j] - mean) * rstd * g0[j] + b0[j]);
    o[4 + j] = f2b((v1[j] - mean) * rstd * g1[j] + b1[j]);
  }
  *(u16x8*)(out + (size_t)row * D_ + lane * 8) = o;
}

// ---------------- QKV GEMM: 128x128, 4 waves, 3-deep counted pipeline ----------------
// Fused epilogue: type-emb + RoPE + scale + head layout. ALL regions store via
// LDS transpose (staging LDS dead after K-loop) with coalesced u16x8 stores.
__global__ __launch_bounds__(256) void gemm_qkv(const u16* __restrict__ A,
    const u16* __restrict__ Bt,
    const int* __restrict__ x_type, const float* __restrict__ type_emb,
    const float* __restrict__ rqc, const float* __restrict__ rqs,
    const float* __restrict__ rkc, const float* __restrict__ rks,
    u16* __restrict__ qT, u16* __restrict__ kT, u16* __restrict__ vT) {
  __shared__ u16 lsmem[6 * 4096];          // 48KB: lA[3][4096] | lB[3][4096]
  u16* lA = lsmem;
  u16* lB = lsmem + 3 * 4096;
  const int K = 512, NK = 16;
  const int tid = threadIdx.x, lane = tid & 63, w = tid >> 6;
  const int wm = w >> 1, wn = w & 1;
  int swz = (blockIdx.x & 7) * 96 + (blockIdx.x >> 3);
  int byy = swz / 12, bxx = swz - byy * 12;
  const size_t bm = (size_t)byy * 128;
  const size_t bn = (size_t)bxx * 128;

  const int r0 = tid >> 2;
  const int cs = ((tid & 3) ^ ((r0 >> 1) & 3)) * 8;
  const u16* a0 = A + (bm + r0) * K + cs;
  const u16* a1 = A + (bm + 64 + r0) * K + cs;
  const u16* b0 = Bt + (bn + r0) * K + cs;
  const u16* b1p = Bt + (bn + 64 + r0) * K + cs;

  int aoff[4], boff[4];
  #pragma unroll
  for (int i = 0; i < 4; i++) {
    int ra = wm * 64 + i * 16 + (lane & 15);
    aoff[i] = ra * 64 + (((lane >> 4) ^ ((ra >> 1) & 3)) * 16);
    int rb = wn * 64 + i * 16 + (lane & 15);
    boff[i] = rb * 64 + (((lane >> 4) ^ ((rb >> 1) & 3)) * 16);
  }

  auto stage = [&](int j, int buf) {      // 4 loads
    char* ad = (char*)lA + buf * 8192 + w * 1024;
    char* bd = (char*)lB + buf * 8192 + w * 1024;
    gld16(a0 + j * 32, ad);
    gld16(a1 + j * 32, ad + 4096);
    gld16(b0 + j * 32, bd);
    gld16(b1p + j * 32, bd + 4096);
  };
  f32x4 acc[4][4] = {};
  auto compute = [&](int buf) {
    const char* lAc = (const char*)lA + buf * 8192;
    const char* lBc = (const char*)lB + buf * 8192;
    bf16x8 af[4], bf[4];
    #pragma unroll
    for (int i = 0; i < 4; i++) af[i] = *(const bf16x8*)(lAc + aoff[i]);
    #pragma unroll
    for (int n = 0; n < 4; n++) bf[n] = *(const bf16x8*)(lBc + boff[n]);
    __builtin_amdgcn_s_setprio(1);
    #pragma unroll
    for (int i = 0; i < 4; i++)
      #pragma unroll
      for (int n = 0; n < 4; n++)
        acc[i][n] = mfma16(af[i], bf[n], acc[i][n]);
    __builtin_amdgcn_s_setprio(0);
  };

  stage(0, 0);
  stage(1, 1);
  int cur = 0;
  for (int j = 0; j < NK - 1; j++) {
    WAITV(4);                              // oldest stage landed; next stays in flight
    __builtin_amdgcn_s_barrier();
    if (j + 2 < NK) { int nb = cur + 2; if (nb >= 3) nb -= 3; stage(j + 2, nb); }
    compute(cur);
    cur = (cur + 1 == 3) ? 0 : cur + 1;
  }
  WAITV(0);
  __builtin_amdgcn_s_barrier();
  compute(cur);

  // fused epilogue. block-uniform region: 0=q (cols 0..511), 1=k, 2=v
  const int region = (int)(bn >> 9);
  __syncthreads();                         // staging LDS dead -> reuse as transpose buf
  u16 (*tbuf)[136] = (u16(*)[136])lsmem;   // 128 x 136 u16 = 34816B <= 48KB
  const int bb = (int)(bm >> 10);
  const int t0 = (int)(bm & 1023);

  if (region < 2) {
    // compute fused value, write TRANSPOSED layout tbuf[t_local][col_local]
    #pragma unroll
    for (int i = 0; i < 4; i++) {
      #pragma unroll
      for (int jj = 0; jj < 4; jj++) {
        int rl = wm * 64 + i * 16 + (lane >> 4) * 4 + jj;   // t-local
        int row = (int)bm + rl;                             // bt index
        int b = row >> 10, t = row & 1023;
        int ty = x_type[b * TP1 + t + region];              // +0 for q, +1 for k
        const float* rc = (region == 0) ? rqc : rkc;
        const float* rs = (region == 0) ? rqs : rks;
        #pragma unroll
        for (int n = 0; n < 4; n++) {
          int cl = wn * 64 + n * 16 + (lane & 15);          // col-local 0..127
          int cloc = ((int)bn - region * 512) + cl;         // 0..511
          int hd = cloc & 63;
          float v = acc[i][n][jj] + type_emb[(size_t)ty * 1024 + region * 512 + cloc];
          float vp = __shfl_xor(v, 1);
          if (hd < 32) {
            int p = hd >> 1;
            float c = rc[row * 16 + p], s = rs[row * 16 + p];
            v = (hd & 1) ? (v * c + vp * s) : (v * c - vp * s);
          }
          if (region == 0) v *= QSCALE;
          tbuf[rl][cl] = f2b(v);
        }
      }
    }
    __syncthreads();
    // coalesced store: 2048 x 16B chunks; chunk -> (t_local, col_chunk)
    u16* dst = (region == 0) ? qT : kT;
    const int h0 = (((int)bn - region * 512) >> 6);         // first of 2 heads
    #pragma unroll
    for (int p = 0; p < 8; p++) {
      int chunk = p * 256 + tid;
      int tl = chunk >> 4;                                  // 0..127
      int cc = (chunk & 15) * 8;                            // 0..120
      u16x8 o = *(const u16x8*)&tbuf[tl][cc];
      *(u16x8*)(dst + ((size_t)(bb * 8 + h0 + (cc >> 6)) * T_ + t0 + tl) * 64 +
                (cc & 63)) = o;
    }
  } else {
    // V region: transpose to hd-major, coalesced u16x8 stores into vT
    #pragma unroll
    for (int i = 0; i < 4; i++) {
      #pragma unroll
      for (int n = 0; n < 4; n++) {
        int cl = wn * 64 + n * 16 + (lane & 15);       // v-col local 0..127
        #pragma unroll
        for (int jj = 0; jj < 4; jj++) {
          int r = wm * 64 + i * 16 + (lane >> 4) * 4 + jj;   // t local 0..127
          tbuf[cl][r] = f2b(acc[i][n][jj]);
        }
      }
    }
    __syncthreads();
    const int h0 = ((int)bn - 1024) >> 6;              // first head (of 2) in this block
    const size_t rbase = (size_t)(bb * 8 + h0) * 64;   // vT row of cl=0
    #pragma unroll
    for (int p = 0; p < 8; p++) {
      int rl = p * 16 + (tid >> 4);                    // 0..127 (hd-major local)
      int c8 = (tid & 15) * 8;                         // t chunk
      u16x8 o = *(const u16x8*)&tbuf[rl][c8];
      *(u16x8*)(vT + (rbase + rl) * T_ + t0 + c8) = o;
    }
  }
}

// ---------------- FF1 GEMM: BM=256 x BN=128, BK=32, 512 thr / 8 waves, 2-phase ----------------
__global__ __launch_bounds__(512) void gemm_ff1(const u16* __restrict__ A,
    const u16* __restrict__ Bt, const float* __restrict__ b1,
    u16* __restrict__ outp) {
  __shared__ u16 lA[2][8192];              // 256 rows x 32 cols per buf (16KB)
  __shared__ u16 lB[2][4096];              // 128 rows x 32 cols per buf (8KB)
  const int K = 512;
  const int tid = threadIdx.x, lane = tid & 63, w = tid >> 6;   // 8 waves
  const int wm = w >> 2, wn = w & 3;
  int swz = (blockIdx.x & 7) * 64 + (blockIdx.x >> 3);          // 512 blocks
  int byy = swz >> 4, bxx = swz & 15;                           // 32 x 16
  const size_t bm = (size_t)byy * 256;
  const size_t bn = (size_t)bxx * 128;

  const int r0 = tid >> 2;                                      // 0..127
  const int cs = ((tid & 3) ^ ((r0 >> 1) & 3)) * 8;
  const u16* a0 = A + (bm + r0) * K + cs;
  const u16* a1 = A + (bm + 128 + r0) * K + cs;
  const u16* b0 = Bt + (bn + r0) * K + cs;

  int aoff[8], boff[2];
  #pragma unroll
  for (int i = 0; i < 8; i++) {
    int ra = wm * 128 + i * 16 + (lane & 15);
    aoff[i] = ra * 64 + (((lane >> 4) ^ ((ra >> 1) & 3)) * 16);
  }
  #pragma unroll
  for (int n = 0; n < 2; n++) {
    int rb = wn * 32 + n * 16 + (lane & 15);
    boff[n] = rb * 64 + (((lane >> 4) ^ ((rb >> 1) & 3)) * 16);
  }

  auto stage = [&](int k0, int buf) {      // 3 gld16 calls (8KB each)
    char* ad = (char*)lA + buf * 16384 + w * 1024;
    char* bd = (char*)lB + buf * 8192 + w * 1024;
    gld16(a0 + k0, ad);                    // A rows 0..127
    gld16(a1 + k0, ad + 8192);             // A rows 128..255
    gld16(b0 + k0, bd);                    // B rows 0..127
  };

  f32x4 acc[8][2] = {};
  stage(0, 0);
  __syncthreads();
  int cur = 0;
  for (int k0 = 0; k0 < K; k0 += 32) {
    if (k0 + 32 < K) stage(k0 + 32, cur ^ 1);
    const char* lAc = (const char*)lA + cur * 16384;
    const char* lBc = (const char*)lB + cur * 8192;
    bf16x8 bf[2];
    #pragma unroll
    for (int n = 0; n < 2; n++) bf[n] = *(const bf16x8*)(lBc + boff[n]);
    __builtin_amdgcn_s_setprio(1);
    #pragma unroll
    for (int i = 0; i < 8; i++) {
      bf16x8 af = *(const bf16x8*)(lAc + aoff[i]);
      acc[i][0] = mfma16(af, bf[0], acc[i][0]);
      acc[i][1] = mfma16(af, bf[1], acc[i][1]);
    }
    __builtin_amdgcn_s_setprio(0);
    __syncthreads();
    cur ^= 1;
  }
  // epilogue: real col c = bn/2 + wn*16 + (lane&15); a = acc[i][0], g = acc[i][1]
  {
    int c = ((int)bn >> 1) + wn * 16 + (lane & 15);
    float bav = b1[c], bgv = b1[1024 + c];
    #pragma unroll
    for (int i = 0; i < 8; i++) {
      #pragma unroll
      for (int jj = 0; jj < 4; jj++) {
        int row = (int)bm + wm * 128 + i * 16 + (lane >> 4) * 4 + jj;
        float av = acc[i][0][jj] + bav;
        float gv = acc[i][1][jj] + bgv;
        float sg = gv / (1.f + expf(-gv));
        outp[(size_t)row * 1024 + c] = f2b(sg * av);
      }
    }
  }
}

// ---------------- FF2 GEMM, 512 thr / 8 waves, 3-deep counted pipeline ----------------
__global__ __launch_bounds__(512) void gemm_ff2(const u16* __restrict__ A,
    const u16* __restrict__ Bt, const float* __restrict__ bias,
    float* __restrict__ C) {
  __shared__ u16 lA[3][4096];
  __shared__ u16 lB[3][4096];
  const int K = 1024, N = 512, NK = 32;
  const int tid = threadIdx.x, lane = tid & 63, w = tid >> 6;   // w 0..7
  const int wm = w >> 2, wn = w & 3;                            // 2x4 waves: 64x32 each
  int swz = (blockIdx.x & 7) * 32 + (blockIdx.x >> 3);          // 256 blocks
  int byy = swz >> 2, bxx = swz & 3;
  const size_t bm = (size_t)byy * 128;
  const size_t bn = (size_t)bxx * 128;

  const int r0 = tid >> 2;                                      // 0..127
  const int cs = ((tid & 3) ^ ((r0 >> 1) & 3)) * 8;
  const u16* a0 = A + (bm + r0) * K + cs;
  const u16* b0 = Bt + (bn + r0) * K + cs;

  int aoff[4], boff[2];
  #pragma unroll
  for (int i = 0; i < 4; i++) {
    int ra = wm * 64 + i * 16 + (lane & 15);
    aoff[i] = ra * 64 + (((lane >> 4) ^ ((ra >> 1) & 3)) * 16);
  }
  #pragma unroll
  for (int n = 0; n < 2; n++) {
    int rb = wn * 32 + n * 16 + (lane & 15);
    boff[n] = rb * 64 + (((lane >> 4) ^ ((rb >> 1) & 3)) * 16);
  }

  auto stage = [&](int j, int buf) {      // 2 loads
    gld16(a0 + j * 32, (char*)lA + buf * 8192 + w * 1024);
    gld16(b0 + j * 32, (char*)lB + buf * 8192 + w * 1024);
  };
  f32x4 acc[4][2] = {};
  auto compute = [&](int buf) {
    const char* lAc = (const char*)lA + buf * 8192;
    const char* lBc = (const char*)lB + buf * 8192;
    bf16x8 af[4], bf[2];
    #pragma unroll
    for (int i = 0; i < 4; i++) af[i] = *(const bf16x8*)(lAc + aoff[i]);
    #pragma unroll
    for (int n = 0; n < 2; n++) bf[n] = *(const bf16x8*)(lBc + boff[n]);
    __builtin_amdgcn_s_setprio(1);
    #pragma unroll
    for (int i = 0; i < 4; i++)
      #pragma unroll
      for (int n = 0; n < 2; n++)
        acc[i][n] = mfma16(af[i], bf[n], acc[i][n]);
    __builtin_amdgcn_s_setprio(0);
  };

  stage(0, 0);
  stage(1, 1);
  int cur = 0;
  for (int j = 0; j < NK - 1; j++) {
    WAITV(2);
    __builtin_amdgcn_s_barrier();
    if (j + 2 < NK) { int nb = cur + 2; if (nb >= 3) nb -= 3; stage(j + 2, nb); }
    compute(cur);
    cur = (cur + 1 == 3) ? 0 : cur + 1;
  }
  WAITV(0);
  __builtin_amdgcn_s_barrier();
  compute(cur);

  #pragma unroll
  for (int i = 0; i < 4; i++) {
    size_t mrow = bm + wm * 64 + i * 16 + (lane >> 4) * 4;
    #pragma unroll
    for (int n = 0; n < 2; n++) {
      size_t col = bn + wn * 32 + n * 16 + (lane & 15);
      float bv = bias[col];
      #pragma unroll
      for (int jj = 0; jj < 4; jj++) {
        size_t idx = (mrow + jj) * (size_t)N + col;
        C[idx] = acc[i][n][jj] + bv + C[idx];   // in-place residual
      }
    }
  }
}

// ---------------- causal flash attention + residual: out = x_value + attn ----------------
// 8 waves / 512 thr / 128 q-rows, 2-phase LDS dbuf with KVBLK=128 (two proven 8KB
// sub-tiles per buffer): jmax = qp+1 barrier-locked iterations (max 8).
__global__ __launch_bounds__(512, 4) void attn_kernel(const u16* __restrict__ qT,
    const u16* __restrict__ kT, const u16* __restrict__ vT,
    const float* __restrict__ xv, float* __restrict__ X) {
  int s0 = (blockIdx.x & 7) * 64 + (blockIdx.x >> 3);   // 512 blocks, 8 bh per XCD
  const int bh = ((blockIdx.x & 7) << 3) + (s0 & 7);    // 8 bh per XCD
  const int qp = 7 - ((s0 >> 3) & 7);                   // true LPT: qp=7 of all bh first
  const int b = bh >> 3, h = bh & 7;
  const int tid = threadIdx.x, lane = tid & 63, w = tid >> 6;   // 8 waves
  const int q = lane & 15, g = lane >> 4;
  __shared__ u16 lK[2][8192];              // [buf][half0 8KB | half1 8KB]
  __shared__ u16 lV[2][8192];

  const int qrow0 = qp * 128 + w * 16;     // this wave's 16-row q-strip
  bf16x8 qf[2];
  {
    const u16* qp_ = qT + ((size_t)bh * T_ + qrow0 + q) * 64 + g * 8;
    qf[0] = *(const bf16x8*)qp_;
    qf[1] = *(const bf16x8*)(qp_ + 32);
  }
  f32x4 acc[4] = {};
  float mr = -1e30f, lr = 0.f;

  const int sr = tid >> 3;                 // 0..63
  const int scs = ((tid & 7) ^ (sr & 7)) * 8;
  const u16* kb = kT + ((size_t)bh * T_ + sr) * 64 + scs;
  const u16* vb = vT + ((size_t)bh * 64 + sr) * T_ + scs;

  auto stage = [&](int j, int buf) {       // K rows [j*128,+128), V cols [j*128,+128)
    char* kd = (char*)lK + buf * 16384 + w * 1024;
    char* vd = (char*)lV + buf * 16384 + w * 1024;
    gld16(kb + (size_t)j * 8192, kd);              // K half0 (rows +0..63)
    gld16(kb + (size_t)j * 8192 + 4096, kd + 8192);// K half1 (rows +64..127)
    gld16(vb + j * 128, vd);                       // V half0 (cols +0..63)
    gld16(vb + j * 128 + 64, vd + 8192);           // V half1 (cols +64..127)
  };

  const int jmax = qp + 1;
  stage(0, 0);
  __syncthreads();
  int cur = 0;
  for (int j = 0; j < jmax; j++) {
    if (j + 1 < jmax) stage(j + 1, cur ^ 1);   // prefetch next 128-tile under compute
    const char* lKc = (const char*)lK + cur * 16384;
    const char* lVc = (const char*)lV + cur * 16384;

    // QK^T swapped: s[n][i] = S[key = j*128 + n*16+g*4+i][qrow0+q]
    f32x4 s[8] = {};
    __builtin_amdgcn_s_setprio(1);
    #pragma unroll
    for (int ka = 0; ka < 2; ka++) {
      #pragma unroll
      for (int n = 0; n < 8; n++) {
        bf16x8 kf = *(const bf16x8*)(lKc + (n >> 2) * 8192 + ((n & 3) * 16 + q) * 128 +
                                     (((ka * 4 + g) ^ (q & 7)) * 16));
        s[n] = mfma16(kf, qf[ka], s[n]);
      }
    }
    __builtin_amdgcn_s_setprio(0);
    if (j == jmax - 1) {                   // diagonal-tile causal mask
      int qrow = w * 16 + q;               // key-local: n*16+g*4+i > w*16+q
      #pragma unroll
      for (int n = 0; n < 8; n++)
        #pragma unroll
        for (int i = 0; i < 4; i++)
          if (n * 16 + g * 4 + i > qrow) s[n][i] = -1e30f;
    }
    // in-register softmax: one q-row per lane (+2 shfl across g-groups)
    float mt = -1e30f;
    #pragma unroll
    for (int n = 0; n < 8; n++)
      mt = fmaxf(mt, fmaxf(fmaxf(s[n][0], s[n][1]), fmaxf(s[n][2], s[n][3])));
    mt = fmaxf(mt, __shfl_xor(mt, 16));
    mt = fmaxf(mt, __shfl_xor(mt, 32));
    if (__any(mt > mr + 8.f)) {            // defer-max: skip rescale when growth < 2^8
      float mnew = fmaxf(mr, mt);
      float sc = exp2f(mr - mnew);
      mr = mnew;
      lr *= sc;
      #pragma unroll
      for (int t = 0; t < 4; t++) acc[t] *= sc;
    }
    float ps = 0.f;
    U8 pa[4];                              // pa[kt] covers keys kt*32..kt*32+31
    #pragma unroll
    for (int kt = 0; kt < 4; kt++) {
      float p0[4], p1[4];
      #pragma unroll
      for (int i = 0; i < 4; i++) {
        p0[i] = exp2f(s[2 * kt][i] - mr);
        p1[i] = exp2f(s[2 * kt + 1][i] - mr);
        ps += p0[i] + p1[i];
      }
      pa[kt].u[0] = cvtpk(p0[0], p0[1]);
      pa[kt].u[1] = cvtpk(p0[2], p0[3]);
      pa[kt].u[2] = cvtpk(p1[0], p1[1]);
      pa[kt].u[3] = cvtpk(p1[2], p1[3]);
    }
    ps += __shfl_xor(ps, 16);
    ps += __shfl_xor(ps, 32);
    lr += ps;
    // PV: O^T[d][q] += V^T[d][k'] P^T[k'][q]; kt half = kt>>1, sub-chunk = kt&1
    __builtin_amdgcn_s_setprio(1);
    #pragma unroll
    for (int t = 0; t < 4; t++) {
      #pragma unroll
      for (int kt = 0; kt < 4; kt++) {
        const char* vrh = lVc + (kt >> 1) * 8192 + (t * 16 + q) * 128 + (g & 1) * 8;
        int ktl = kt & 1;
        u32x2 lo = *(const u32x2*)(vrh + (((ktl * 4 + (g >> 1)) ^ (q & 7)) * 16));
        u32x2 hi = *(const u32x2*)(vrh + (((ktl * 4 + 2 + (g >> 1)) ^ (q & 7)) * 16));
        U8 af;
        af.u[0] = lo[0]; af.u[1] = lo[1]; af.u[2] = hi[0]; af.u[3] = hi[1];
        acc[t] = mfma16(af.v, pa[kt].v, acc[t]);
      }
    }
    __builtin_amdgcn_s_setprio(0);
    __syncthreads();                       // drains prefetch; publishes buf cur^1
    cur ^= 1;
  }
  // epilogue: lane owns q-row (qrow0+q), cols d = t*16+g*4+{0..3} -> f32x4
  {
    float inv = 1.f / lr;
    size_t base = ((size_t)b * T_ + qrow0 + q) * D_ + h * 64 + g * 4;
    #pragma unroll
    for (int t = 0; t < 4; t++) {
      f32x4 r = *(const f32x4*)(xv + base + t * 16);
      f32x4 o;
      #pragma unroll
      for (int i = 0; i < 4; i++) o[i] = r[i] + acc[t][i] * inv;
      *(f32x4*)(X + base + t * 16) = o;
    }
  }
}

// ------------------------------- launch -------------------------------
extern "C" void kernel_launch(void* const* d_in, const int* in_sizes, int n_in,
                              void* d_out, int out_size, void* d_ws, size_t ws_size,
                              hipStream_t stream) {
  const int*   x_type   = (const int*)d_in[0];
  const float* x_value  = (const float*)d_in[1];
  const float* seq      = (const float*)d_in[2];
  const float* W_attn   = (const float*)d_in[3];
  const float* type_emb = (const float*)d_in[4];
  const float* ln1_g    = (const float*)d_in[5];
  const float* ln1_b    = (const float*)d_in[6];
  const float* ln2_g    = (const float*)d_in[7];
  const float* ln2_b    = (const float*)d_in[8];
  const float* W1       = (const float*)d_in[9];
  const float* b1       = (const float*)d_in[10];
  const float* W2       = (const float*)d_in[11];
  const float* b2       = (const float*)d_in[12];
  float* out = (float*)d_out;
  char* ws = (char*)d_ws;

  // workspace layout — total ~38.5 MiB
  u16*   WtA  = (u16*)(ws + 0);             // 1536x512 bf16  1.5 MiB
  u16*   W1i  = (u16*)(ws + 1572864);       // 2048x512 bf16 interleaved a/gate  2 MiB
  u16*   W2t  = (u16*)(ws + 3670016);       // 512x1024 bf16  1 MiB
  float* rqc  = (float*)(ws + 4718592);     // 4 rope tables, 512 KiB each
  float* rqs  = (float*)(ws + 5242880);
  float* rkc  = (float*)(ws + 5767168);
  float* rks  = (float*)(ws + 6291456);
  u16*   hbuf = (u16*)(ws + 6815744);       // 8192x512 bf16 (h, then h2)  8 MiB
  u16*   qTb  = (u16*)(ws + 15204352);      // (B,H,T,64) bf16  8 MiB
  u16*   kTb  = (u16*)(ws + 23592960);      // 8 MiB
  u16*   vTb  = (u16*)(ws + 31981568);      // (B,H,64,T) bf16  8 MiB
  u16*   ff1a = (u16*)(ws + 15204352);      // 8192x1024 bf16 16 MiB, aliases qT+kT (dead post-attn)

  prep_kernel<<<1088, 256, 0, stream>>>(W_attn, W1, W2, seq, WtA, W1i, W2t,
                                        rqc, rqs, rkc, rks);
  ln_kernel<<<B_ * T_ / 4, 256, 0, stream>>>(x_value, ln1_g, ln1_b, hbuf);
  gemm_qkv<<<768, 256, 0, stream>>>(hbuf, WtA, x_type, type_emb,
                                    rqc, rqs, rkc, rks, qTb, kTb, vTb);
  attn_kernel<<<512, 512, 0, stream>>>(qTb, kTb, vTb, x_value, out);
  ln_kernel<<<B_ * T_ / 4, 256, 0, stream>>>(out, ln2_g, ln2_b, hbuf);
  gemm_ff1<<<512, 512, 0, stream>>>(hbuf, W1i, b1, ff1a);
  gemm_ff2<<<256, 512, 0, stream>>>(ff1a, W2t, b2, out);
}

// Round 16
// 119.109 us; speedup vs baseline: 1.1778x; 1.0372x over previous
//
#include <hip/hip_runtime.h>
#include <stdint.h>
#include <math.h>

typedef unsigned short u16;
typedef unsigned int u32;
typedef __attribute__((ext_vector_type(8))) short bf16x8;   // 8 bf16 (4 VGPRs) MFMA A/B frag
typedef __attribute__((ext_vector_type(4))) float f32x4;
typedef __attribute__((ext_vector_type(2))) float f32x2;
typedef __attribute__((ext_vector_type(2))) u16 u16x2;
typedef __attribute__((ext_vector_type(8))) u16 u16x8;
typedef __attribute__((ext_vector_type(2))) u32 u32x2;

#define B_ 8
#define T_ 1024
#define D_ 512
#define H_ 8
#define TP1 1025
// q scale: 1/sqrt(64) * log2(e)  (softmax runs in exp2 domain)
#define QSCALE 0.1803368801111204f

__device__ __forceinline__ u16 f2b(float f) {           // f32 -> bf16 RNE
  union { float f; u32 u; } v; v.f = f;
  return (u16)((v.u + 0x7fffu + ((v.u >> 16) & 1u)) >> 16);
}
__device__ __forceinline__ void gld16(const void* g, void* l) {
  // async global->LDS, 16B/lane; LDS dest = wave-uniform base + lane*16
  __builtin_amdgcn_global_load_lds((const __attribute__((address_space(1))) u32*)g,
                                   (__attribute__((address_space(3))) u32*)l, 16, 0, 0);
}
__device__ __forceinline__ f32x4 mfma16(bf16x8 a, bf16x8 b, f32x4 c) {
  return __builtin_amdgcn_mfma_f32_16x16x32_bf16(a, b, c, 0, 0, 0);
}
__device__ __forceinline__ u32 cvtpk(float lo, float hi) {   // 2xf32 -> packed bf16x2 (RNE)
  u32 r;
  asm("v_cvt_pk_bf16_f32 %0, %1, %2" : "=v"(r) : "v"(lo), "v"(hi));
  return r;
}
union U8 { u32 u[4]; bf16x8 v; };

// counted-vmcnt waits: wait for the OLDEST stage only, keep the rest in flight
#define WAITV(N) asm volatile("s_waitcnt vmcnt(" #N ")" ::: "memory")

// ---------------- fused prep: weight transposes + rope tables + LN1 ----------------
// blocks 0..575 weight transposes, 576..1087 rope, 1088..3135 LN1 (x_value -> hbuf)
__global__ __launch_bounds__(256) void prep_kernel(const float* __restrict__ W_attn,
    const float* __restrict__ W1, const float* __restrict__ W2,
    const float* __restrict__ seq,
    u16* __restrict__ WtA, u16* __restrict__ W1i, u16* __restrict__ W2t,
    float* __restrict__ cq, float* __restrict__ sq_,
    float* __restrict__ ck, float* __restrict__ sk,
    const float* __restrict__ xv, const float* __restrict__ ln1g,
    const float* __restrict__ ln1b, u16* __restrict__ hbuf) {
  int bid = blockIdx.x, tid = threadIdx.x;
  if (bid >= 1088) {                       // LN1: 8192 rows, 4 rows/block
    int row = (bid - 1088) * 4 + (tid >> 6);
    int lane = tid & 63;
    const float* xr = xv + (size_t)row * D_ + lane * 8;
    f32x4 v0 = *(const f32x4*)xr;
    f32x4 v1 = *(const f32x4*)(xr + 4);
    float s = 0.f, sq = 0.f;
    #pragma unroll
    for (int j = 0; j < 4; j++) { s += v0[j] + v1[j]; sq += v0[j] * v0[j] + v1[j] * v1[j]; }
    #pragma unroll
    for (int m = 1; m < 64; m <<= 1) { s += __shfl_xor(s, m); sq += __shfl_xor(sq, m); }
    float mean = s * (1.f / D_);
    float var = sq * (1.f / D_) - mean * mean;
    float rstd = rsqrtf(var + 1e-5f);
    f32x4 g0 = *(const f32x4*)(ln1g + lane * 8);
    f32x4 g1 = *(const f32x4*)(ln1g + lane * 8 + 4);
    f32x4 b0 = *(const f32x4*)(ln1b + lane * 8);
    f32x4 b1 = *(const f32x4*)(ln1b + lane * 8 + 4);
    u16x8 o;
    #pragma unroll
    for (int j = 0; j < 4; j++) {
      o[j]     = f2b((v0[j] - mean) * rstd * g0[j] + b0[j]);
      o[4 + j] = f2b((v1[j] - mean) * rstd * g1[j] + b1[j]);
    }
    *(u16x8*)(hbuf + (size_t)row * D_ + lane * 8) = o;
    return;
  }
  if (bid >= 576) {                        // rope: B*T*16 elements
    int i = (bid - 576) * 256 + tid;
    int p = i & 15, bt = i >> 4, b = bt >> 10, t = bt & 1023;
    float inv = expf(-(float)p * 0.5756462732485115f);   // 10000^(-p/16)
    float aq = seq[b * TP1 + t] * inv;
    float ak = seq[b * TP1 + t + 1] * inv;
    cq[i] = cosf(aq); sq_[i] = sinf(aq);
    ck[i] = cosf(ak); sk[i] = sinf(ak);
    return;
  }
  __shared__ u16 lt[64][65];
  const float* src; u16* dst; int ld, Kd, k0, r0; bool ilv = false;
  if (bid < 192) {            // WtA: 8 k-tiles x 24 n-tiles
    src = W_attn; dst = WtA; ld = 1536; Kd = 512;
    k0 = (bid & 7) * 64; r0 = (bid >> 3) * 64;
  } else if (bid < 448) {     // W1i: 8 k-tiles x 32 r-tiles, interleaved
    int t = bid - 192;
    src = W1; dst = W1i; ld = 2048; Kd = 512; ilv = true;
    k0 = (t & 7) * 64; r0 = (t >> 3) * 64;
  } else {                    // W2t: 16 k-tiles x 8 n-tiles
    int t = bid - 448;
    src = W2; dst = W2t; ld = 512; Kd = 1024;
    k0 = (t & 15) * 64; r0 = (t >> 4) * 64;
  }
  int nl = tid & 63;
  int scol, rloc;
  if (ilv) {
    if (nl < 32) { scol = (r0 >> 1) + nl;          rloc = ((nl >> 4) << 5) + (nl & 15); }
    else         { scol = 1024 + (r0 >> 1) + (nl - 32); rloc = (((nl - 32) >> 4) << 5) + 16 + (nl & 15); }
  } else { scol = r0 + nl; rloc = nl; }
  #pragma unroll
  for (int it = 0; it < 16; it++) {
    int kl = (tid >> 6) * 16 + it;
    lt[rloc][kl] = f2b(src[(size_t)(k0 + kl) * ld + scol]);
  }
  __syncthreads();
  #pragma unroll
  for (int it = 0; it < 16; it++) {
    int rl = (tid >> 6) * 16 + it;
    dst[(size_t)(r0 + rl) * Kd + k0 + nl] = lt[rl][nl];
  }
}

// ---------------- LayerNorm (ln2): one WAVE per row, no LDS, no barriers ----------------
__global__ __launch_bounds__(256) void ln_kernel(const float* __restrict__ x,
    const float* __restrict__ g, const float* __restrict__ bta, u16* __restrict__ out) {
  int row = blockIdx.x * 4 + (threadIdx.x >> 6);    // 8192 rows, 4 rows/block
  int lane = threadIdx.x & 63;
  const float* xr = x + (size_t)row * D_ + lane * 8;
  f32x4 v0 = *(const f32x4*)xr;
  f32x4 v1 = *(const f32x4*)(xr + 4);
  float s = 0.f, sq = 0.f;
  #pragma unroll
  for (int j = 0; j < 4; j++) { s += v0[j] + v1[j]; sq += v0[j] * v0[j] + v1[j] * v1[j]; }
  #pragma unroll
  for (int m = 1; m < 64; m <<= 1) { s += __shfl_xor(s, m); sq += __shfl_xor(sq, m); }
  float mean = s * (1.f / D_);
  float var = sq * (1.f / D_) - mean * mean;
  float rstd = rsqrtf(var + 1e-5f);
  f32x4 g0 = *(const f32x4*)(g + lane * 8);
  f32x4 g1 = *(const f32x4*)(g + lane * 8 + 4);
  f32x4 b0 = *(const f32x4*)(bta + lane * 8);
  f32x4 b1 = *(const f32x4*)(bta + lane * 8 + 4);
  u16x8 o;
  #pragma unroll
  for (int j = 0; j < 4; j++) {
    o[j]     = f2b((v0[j] - mean) * rstd * g0[j] + b0[j]);
    o[4 + j] = f2b((v1[j] - mean) * rstd * g1[j] + b1[j]);
  }
  *(u16x8*)(out + (size_t)row * D_ + lane * 8) = o;
}

// ---------------- QKV GEMM: 128x128, 4 waves, 3-deep counted pipeline ----------------
// Fused epilogue: type-emb + RoPE + scale + head layout. ALL regions store via
// LDS transpose (staging LDS dead after K-loop) with coalesced u16x8 stores.
__global__ __launch_bounds__(256) void gemm_qkv(const u16* __restrict__ A,
    const u16* __restrict__ Bt,
    const int* __restrict__ x_type, const float* __restrict__ type_emb,
    const float* __restrict__ rqc, const float* __restrict__ rqs,
    const float* __restrict__ rkc, const float* __restrict__ rks,
    u16* __restrict__ qT, u16* __restrict__ kT, u16* __restrict__ vT) {
  __shared__ u16 lsmem[6 * 4096];          // 48KB: lA[3][4096] | lB[3][4096]
  u16* lA = lsmem;
  u16* lB = lsmem + 3 * 4096;
  const int K = 512, NK = 16;
  const int tid = threadIdx.x, lane = tid & 63, w = tid >> 6;
  const int wm = w >> 1, wn = w & 1;
  int swz = (blockIdx.x & 7) * 96 + (blockIdx.x >> 3);
  int byy = swz / 12, bxx = swz - byy * 12;
  const size_t bm = (size_t)byy * 128;
  const size_t bn = (size_t)bxx * 128;

  const int r0 = tid >> 2;
  const int cs = ((tid & 3) ^ ((r0 >> 1) & 3)) * 8;
  const u16* a0 = A + (bm + r0) * K + cs;
  const u16* a1 = A + (bm + 64 + r0) * K + cs;
  const u16* b0 = Bt + (bn + r0) * K + cs;
  const u16* b1p = Bt + (bn + 64 + r0) * K + cs;

  int aoff[4], boff[4];
  #pragma unroll
  for (int i = 0; i < 4; i++) {
    int ra = wm * 64 + i * 16 + (lane & 15);
    aoff[i] = ra * 64 + (((lane >> 4) ^ ((ra >> 1) & 3)) * 16);
    int rb = wn * 64 + i * 16 + (lane & 15);
    boff[i] = rb * 64 + (((lane >> 4) ^ ((rb >> 1) & 3)) * 16);
  }

  auto stage = [&](int j, int buf) {      // 4 loads
    char* ad = (char*)lA + buf * 8192 + w * 1024;
    char* bd = (char*)lB + buf * 8192 + w * 1024;
    gld16(a0 + j * 32, ad);
    gld16(a1 + j * 32, ad + 4096);
    gld16(b0 + j * 32, bd);
    gld16(b1p + j * 32, bd + 4096);
  };
  f32x4 acc[4][4] = {};
  auto compute = [&](int buf) {
    const char* lAc = (const char*)lA + buf * 8192;
    const char* lBc = (const char*)lB + buf * 8192;
    bf16x8 af[4], bf[4];
    #pragma unroll
    for (int i = 0; i < 4; i++) af[i] = *(const bf16x8*)(lAc + aoff[i]);
    #pragma unroll
    for (int n = 0; n < 4; n++) bf[n] = *(const bf16x8*)(lBc + boff[n]);
    __builtin_amdgcn_s_setprio(1);
    #pragma unroll
    for (int i = 0; i < 4; i++)
      #pragma unroll
      for (int n = 0; n < 4; n++)
        acc[i][n] = mfma16(af[i], bf[n], acc[i][n]);
    __builtin_amdgcn_s_setprio(0);
  };

  stage(0, 0);
  stage(1, 1);
  int cur = 0;
  for (int j = 0; j < NK - 1; j++) {
    WAITV(4);                              // oldest stage landed; next stays in flight
    __builtin_amdgcn_s_barrier();
    if (j + 2 < NK) { int nb = cur + 2; if (nb >= 3) nb -= 3; stage(j + 2, nb); }
    compute(cur);
    cur = (cur + 1 == 3) ? 0 : cur + 1;
  }
  WAITV(0);
  __builtin_amdgcn_s_barrier();
  compute(cur);

  // fused epilogue. block-uniform region: 0=q (cols 0..511), 1=k, 2=v
  const int region = (int)(bn >> 9);
  __syncthreads();                         // staging LDS dead -> reuse as transpose buf
  u16 (*tbuf)[136] = (u16(*)[136])lsmem;   // 128 x 136 u16 = 34816B <= 48KB
  const int bb = (int)(bm >> 10);
  const int t0 = (int)(bm & 1023);

  if (region < 2) {
    // compute fused value, write TRANSPOSED layout tbuf[t_local][col_local]
    #pragma unroll
    for (int i = 0; i < 4; i++) {
      #pragma unroll
      for (int jj = 0; jj < 4; jj++) {
        int rl = wm * 64 + i * 16 + (lane >> 4) * 4 + jj;   // t-local
        int row = (int)bm + rl;                             // bt index
        int b = row >> 10, t = row & 1023;
        int ty = x_type[b * TP1 + t + region];              // +0 for q, +1 for k
        const float* rc = (region == 0) ? rqc : rkc;
        const float* rs = (region == 0) ? rqs : rks;
        #pragma unroll
        for (int n = 0; n < 4; n++) {
          int cl = wn * 64 + n * 16 + (lane & 15);          // col-local 0..127
          int cloc = ((int)bn - region * 512) + cl;         // 0..511
          int hd = cloc & 63;
          float v = acc[i][n][jj] + type_emb[(size_t)ty * 1024 + region * 512 + cloc];
          float vp = __shfl_xor(v, 1);
          if (hd < 32) {
            int p = hd >> 1;
            float c = rc[row * 16 + p], s = rs[row * 16 + p];
            v = (hd & 1) ? (v * c + vp * s) : (v * c - vp * s);
          }
          if (region == 0) v *= QSCALE;
          tbuf[rl][cl] = f2b(v);
        }
      }
    }
    __syncthreads();
    // coalesced store: 2048 x 16B chunks; chunk -> (t_local, col_chunk)
    u16* dst = (region == 0) ? qT : kT;
    const int h0 = (((int)bn - region * 512) >> 6);         // first of 2 heads
    #pragma unroll
    for (int p = 0; p < 8; p++) {
      int chunk = p * 256 + tid;
      int tl = chunk >> 4;                                  // 0..127
      int cc = (chunk & 15) * 8;                            // 0..120
      u16x8 o = *(const u16x8*)&tbuf[tl][cc];
      *(u16x8*)(dst + ((size_t)(bb * 8 + h0 + (cc >> 6)) * T_ + t0 + tl) * 64 +
                (cc & 63)) = o;
    }
  } else {
    // V region: transpose to hd-major, coalesced u16x8 stores into vT
    #pragma unroll
    for (int i = 0; i < 4; i++) {
      #pragma unroll
      for (int n = 0; n < 4; n++) {
        int cl = wn * 64 + n * 16 + (lane & 15);       // v-col local 0..127
        #pragma unroll
        for (int jj = 0; jj < 4; jj++) {
          int r = wm * 64 + i * 16 + (lane >> 4) * 4 + jj;   // t local 0..127
          tbuf[cl][r] = f2b(acc[i][n][jj]);
        }
      }
    }
    __syncthreads();
    const int h0 = ((int)bn - 1024) >> 6;              // first head (of 2) in this block
    const size_t rbase = (size_t)(bb * 8 + h0) * 64;   // vT row of cl=0
    #pragma unroll
    for (int p = 0; p < 8; p++) {
      int rl = p * 16 + (tid >> 4);                    // 0..127 (hd-major local)
      int c8 = (tid & 15) * 8;                         // t chunk
      u16x8 o = *(const u16x8*)&tbuf[rl][c8];
      *(u16x8*)(vT + (rbase + rl) * T_ + t0 + c8) = o;
    }
  }
}

// ---------------- FF1 GEMM: BM=256 x BN=128, BK=32, 512 thr / 8 waves, 2-phase ----------------
// SwiGLU epilogue routed through dead staging LDS for coalesced u16x8 stores.
__global__ __launch_bounds__(512) void gemm_ff1(const u16* __restrict__ A,
    const u16* __restrict__ Bt, const float* __restrict__ b1,
    u16* __restrict__ outp) {
  __shared__ u16 lsmem[24576];             // 48KB: lA 2x8192 | lB 2x4096
  u16* lA = lsmem;                         // [2][8192]
  u16* lB = lsmem + 16384;                 // [2][4096]
  const int K = 512;
  const int tid = threadIdx.x, lane = tid & 63, w = tid >> 6;   // 8 waves
  const int wm = w >> 2, wn = w & 3;
  int swz = (blockIdx.x & 7) * 64 + (blockIdx.x >> 3);          // 512 blocks
  int byy = swz >> 4, bxx = swz & 15;                           // 32 x 16
  const size_t bm = (size_t)byy * 256;
  const size_t bn = (size_t)bxx * 128;

  const int r0 = tid >> 2;                                      // 0..127
  const int cs = ((tid & 3) ^ ((r0 >> 1) & 3)) * 8;
  const u16* a0 = A + (bm + r0) * K + cs;
  const u16* a1 = A + (bm + 128 + r0) * K + cs;
  const u16* b0 = Bt + (bn + r0) * K + cs;

  int aoff[8], boff[2];
  #pragma unroll
  for (int i = 0; i < 8; i++) {
    int ra = wm * 128 + i * 16 + (lane & 15);
    aoff[i] = ra * 64 + (((lane >> 4) ^ ((ra >> 1) & 3)) * 16);
  }
  #pragma unroll
  for (int n = 0; n < 2; n++) {
    int rb = wn * 32 + n * 16 + (lane & 15);
    boff[n] = rb * 64 + (((lane >> 4) ^ ((rb >> 1) & 3)) * 16);
  }

  auto stage = [&](int k0, int buf) {      // 3 gld16 calls (8KB each)
    char* ad = (char*)lA + buf * 16384 + w * 1024;
    char* bd = (char*)lB + buf * 8192 + w * 1024;
    gld16(a0 + k0, ad);                    // A rows 0..127
    gld16(a1 + k0, ad + 8192);             // A rows 128..255
    gld16(b0 + k0, bd);                    // B rows 0..127
  };

  f32x4 acc[8][2] = {};
  stage(0, 0);
  __syncthreads();
  int cur = 0;
  for (int k0 = 0; k0 < K; k0 += 32) {
    if (k0 + 32 < K) stage(k0 + 32, cur ^ 1);
    const char* lAc = (const char*)lA + cur * 16384;
    const char* lBc = (const char*)lB + cur * 8192;
    bf16x8 bf[2];
    #pragma unroll
    for (int n = 0; n < 2; n++) bf[n] = *(const bf16x8*)(lBc + boff[n]);
    __builtin_amdgcn_s_setprio(1);
    #pragma unroll
    for (int i = 0; i < 8; i++) {
      bf16x8 af = *(const bf16x8*)(lAc + aoff[i]);
      acc[i][0] = mfma16(af, bf[0], acc[i][0]);
      acc[i][1] = mfma16(af, bf[1], acc[i][1]);
    }
    __builtin_amdgcn_s_setprio(0);
    __syncthreads();
    cur ^= 1;
  }
  // SwiGLU epilogue through dead staging LDS: tbuf[row_local 256][col_local 64+pad]
  __syncthreads();
  u16 (*tbuf)[72] = (u16(*)[72])lsmem;     // 256 x 72 u16 = 36864B <= 48KB, 16B rows
  {
    int cl = wn * 16 + (lane & 15);        // col-local 0..63
    int c = ((int)bn >> 1) + cl;
    float bav = b1[c], bgv = b1[1024 + c];
    #pragma unroll
    for (int i = 0; i < 8; i++) {
      #pragma unroll
      for (int jj = 0; jj < 4; jj++) {
        int rl = wm * 128 + i * 16 + (lane >> 4) * 4 + jj;
        float av = acc[i][0][jj] + bav;
        float gv = acc[i][1][jj] + bgv;
        float sg = gv / (1.f + expf(-gv));
        tbuf[rl][cl] = f2b(sg * av);
      }
    }
  }
  __syncthreads();
  {
    const int c0 = ((int)bn >> 1);
    #pragma unroll
    for (int p = 0; p < 4; p++) {
      int ch = p * 512 + tid;              // 2048 chunks
      int rl = ch >> 3;                    // 0..255
      int cc = (ch & 7) * 8;               // 0..56
      u16x8 o = *(const u16x8*)&tbuf[rl][cc];
      *(u16x8*)(outp + (size_t)((int)bm + rl) * 1024 + c0 + cc) = o;
    }
  }
}

// ---------------- FF2 GEMM, 512 thr / 8 waves, 3-deep counted pipeline ----------------
__global__ __launch_bounds__(512) void gemm_ff2(const u16* __restrict__ A,
    const u16* __restrict__ Bt, const float* __restrict__ bias,
    float* __restrict__ C) {
  __shared__ u16 lA[3][4096];
  __shared__ u16 lB[3][4096];
  const int K = 1024, N = 512, NK = 32;
  const int tid = threadIdx.x, lane = tid & 63, w = tid >> 6;   // w 0..7
  const int wm = w >> 2, wn = w & 3;                            // 2x4 waves: 64x32 each
  int swz = (blockIdx.x & 7) * 32 + (blockIdx.x >> 3);          // 256 blocks
  int byy = swz >> 2, bxx = swz & 3;
  const size_t bm = (size_t)byy * 128;
  const size_t bn = (size_t)bxx * 128;

  const int r0 = tid >> 2;                                      // 0..127
  const int cs = ((tid & 3) ^ ((r0 >> 1) & 3)) * 8;
  const u16* a0 = A + (bm + r0) * K + cs;
  const u16* b0 = Bt + (bn + r0) * K + cs;

  int aoff[4], boff[2];
  #pragma unroll
  for (int i = 0; i < 4; i++) {
    int ra = wm * 64 + i * 16 + (lane & 15);
    aoff[i] = ra * 64 + (((lane >> 4) ^ ((ra >> 1) & 3)) * 16);
  }
  #pragma unroll
  for (int n = 0; n < 2; n++) {
    int rb = wn * 32 + n * 16 + (lane & 15);
    boff[n] = rb * 64 + (((lane >> 4) ^ ((rb >> 1) & 3)) * 16);
  }

  auto stage = [&](int j, int buf) {      // 2 loads
    gld16(a0 + j * 32, (char*)lA + buf * 8192 + w * 1024);
    gld16(b0 + j * 32, (char*)lB + buf * 8192 + w * 1024);
  };
  f32x4 acc[4][2] = {};
  auto compute = [&](int buf) {
    const char* lAc = (const char*)lA + buf * 8192;
    const char* lBc = (const char*)lB + buf * 8192;
    bf16x8 af[4], bf[2];
    #pragma unroll
    for (int i = 0; i < 4; i++) af[i] = *(const bf16x8*)(lAc + aoff[i]);
    #pragma unroll
    for (int n = 0; n < 2; n++) bf[n] = *(const bf16x8*)(lBc + boff[n]);
    __builtin_amdgcn_s_setprio(1);
    #pragma unroll
    for (int i = 0; i < 4; i++)
      #pragma unroll
      for (int n = 0; n < 2; n++)
        acc[i][n] = mfma16(af[i], bf[n], acc[i][n]);
    __builtin_amdgcn_s_setprio(0);
  };

  stage(0, 0);
  stage(1, 1);
  int cur = 0;
  for (int j = 0; j < NK - 1; j++) {
    WAITV(2);
    __builtin_amdgcn_s_barrier();
    if (j + 2 < NK) { int nb = cur + 2; if (nb >= 3) nb -= 3; stage(j + 2, nb); }
    compute(cur);
    cur = (cur + 1 == 3) ? 0 : cur + 1;
  }
  WAITV(0);
  __builtin_amdgcn_s_barrier();
  compute(cur);

  #pragma unroll
  for (int i = 0; i < 4; i++) {
    size_t mrow = bm + wm * 64 + i * 16 + (lane >> 4) * 4;
    #pragma unroll
    for (int n = 0; n < 2; n++) {
      size_t col = bn + wn * 32 + n * 16 + (lane & 15);
      float bv = bias[col];
      #pragma unroll
      for (int jj = 0; jj < 4; jj++) {
        size_t idx = (mrow + jj) * (size_t)N + col;
        C[idx] = acc[i][n][jj] + bv + C[idx];   // in-place residual
      }
    }
  }
}

// ---------------- causal flash attention + residual: out = x_value + attn ----------------
// 8 waves / 512 thr / 128 q-rows, 2-phase LDS dbuf with KVBLK=128 (two proven 8KB
// sub-tiles per buffer): jmax = qp+1 barrier-locked iterations (max 8).
__global__ __launch_bounds__(512, 4) void attn_kernel(const u16* __restrict__ qT,
    const u16* __restrict__ kT, const u16* __restrict__ vT,
    const float* __restrict__ xv, float* __restrict__ X) {
  int s0 = (blockIdx.x & 7) * 64 + (blockIdx.x >> 3);   // 512 blocks, 8 bh per XCD
  const int bh = ((blockIdx.x & 7) << 3) + (s0 & 7);    // 8 bh per XCD
  const int qp = 7 - ((s0 >> 3) & 7);                   // true LPT: qp=7 of all bh first
  const int b = bh >> 3, h = bh & 7;
  const int tid = threadIdx.x, lane = tid & 63, w = tid >> 6;   // 8 waves
  const int q = lane & 15, g = lane >> 4;
  __shared__ u16 lK[2][8192];              // [buf][half0 8KB | half1 8KB]
  __shared__ u16 lV[2][8192];

  const int qrow0 = qp * 128 + w * 16;     // this wave's 16-row q-strip
  bf16x8 qf[2];
  {
    const u16* qp_ = qT + ((size_t)bh * T_ + qrow0 + q) * 64 + g * 8;
    qf[0] = *(const bf16x8*)qp_;
    qf[1] = *(const bf16x8*)(qp_ + 32);
  }
  f32x4 acc[4] = {};
  float mr = -1e30f, lr = 0.f;

  const int sr = tid >> 3;                 // 0..63
  const int scs = ((tid & 7) ^ (sr & 7)) * 8;
  const u16* kb = kT + ((size_t)bh * T_ + sr) * 64 + scs;
  const u16* vb = vT + ((size_t)bh * 64 + sr) * T_ + scs;

  auto stage = [&](int j, int buf) {       // K rows [j*128,+128), V cols [j*128,+128)
    char* kd = (char*)lK + buf * 16384 + w * 1024;
    char* vd = (char*)lV + buf * 16384 + w * 1024;
    gld16(kb + (size_t)j * 8192, kd);              // K half0 (rows +0..63)
    gld16(kb + (size_t)j * 8192 + 4096, kd + 8192);// K half1 (rows +64..127)
    gld16(vb + j * 128, vd);                       // V half0 (cols +0..63)
    gld16(vb + j * 128 + 64, vd + 8192);           // V half1 (cols +64..127)
  };

  const int jmax = qp + 1;
  stage(0, 0);
  __syncthreads();
  int cur = 0;
  for (int j = 0; j < jmax; j++) {
    if (j + 1 < jmax) stage(j + 1, cur ^ 1);   // prefetch next 128-tile under compute
    const char* lKc = (const char*)lK + cur * 16384;
    const char* lVc = (const char*)lV + cur * 16384;

    // QK^T swapped: s[n][i] = S[key = j*128 + n*16+g*4+i][qrow0+q]
    f32x4 s[8] = {};
    __builtin_amdgcn_s_setprio(1);
    #pragma unroll
    for (int ka = 0; ka < 2; ka++) {
      #pragma unroll
      for (int n = 0; n < 8; n++) {
        bf16x8 kf = *(const bf16x8*)(lKc + (n >> 2) * 8192 + ((n & 3) * 16 + q) * 128 +
                                     (((ka * 4 + g) ^ (q & 7)) * 16));
        s[n] = mfma16(kf, qf[ka], s[n]);
      }
    }
    __builtin_amdgcn_s_setprio(0);
    if (j == jmax - 1) {                   // diagonal-tile causal mask
      int qrow = w * 16 + q;               // key-local: n*16+g*4+i > w*16+q
      #pragma unroll
      for (int n = 0; n < 8; n++)
        #pragma unroll
        for (int i = 0; i < 4; i++)
          if (n * 16 + g * 4 + i > qrow) s[n][i] = -1e30f;
    }
    // in-register softmax: one q-row per lane (+2 shfl across g-groups)
    float mt = -1e30f;
    #pragma unroll
    for (int n = 0; n < 8; n++)
      mt = fmaxf(mt, fmaxf(fmaxf(s[n][0], s[n][1]), fmaxf(s[n][2], s[n][3])));
    mt = fmaxf(mt, __shfl_xor(mt, 16));
    mt = fmaxf(mt, __shfl_xor(mt, 32));
    if (__any(mt > mr + 8.f)) {            // defer-max: skip rescale when growth < 2^8
      float mnew = fmaxf(mr, mt);
      float sc = exp2f(mr - mnew);
      mr = mnew;
      lr *= sc;
      #pragma unroll
      for (int t = 0; t < 4; t++) acc[t] *= sc;
    }
    float ps = 0.f;
    U8 pa[4];                              // pa[kt] covers keys kt*32..kt*32+31
    #pragma unroll
    for (int kt = 0; kt < 4; kt++) {
      float p0[4], p1[4];
      #pragma unroll
      for (int i = 0; i < 4; i++) {
        p0[i] = exp2f(s[2 * kt][i] - mr);
        p1[i] = exp2f(s[2 * kt + 1][i] - mr);
        ps += p0[i] + p1[i];
      }
      pa[kt].u[0] = cvtpk(p0[0], p0[1]);
      pa[kt].u[1] = cvtpk(p0[2], p0[3]);
      pa[kt].u[2] = cvtpk(p1[0], p1[1]);
      pa[kt].u[3] = cvtpk(p1[2], p1[3]);
    }
    ps += __shfl_xor(ps, 16);
    ps += __shfl_xor(ps, 32);
    lr += ps;
    // PV: O^T[d][q] += V^T[d][k'] P^T[k'][q]; kt half = kt>>1, sub-chunk = kt&1
    __builtin_amdgcn_s_setprio(1);
    #pragma unroll
    for (int t = 0; t < 4; t++) {
      #pragma unroll
      for (int kt = 0; kt < 4; kt++) {
        const char* vrh = lVc + (kt >> 1) * 8192 + (t * 16 + q) * 128 + (g & 1) * 8;
        int ktl = kt & 1;
        u32x2 lo = *(const u32x2*)(vrh + (((ktl * 4 + (g >> 1)) ^ (q & 7)) * 16));
        u32x2 hi = *(const u32x2*)(vrh + (((ktl * 4 + 2 + (g >> 1)) ^ (q & 7)) * 16));
        U8 af;
        af.u[0] = lo[0]; af.u[1] = lo[1]; af.u[2] = hi[0]; af.u[3] = hi[1];
        acc[t] = mfma16(af.v, pa[kt].v, acc[t]);
      }
    }
    __builtin_amdgcn_s_setprio(0);
    __syncthreads();                       // drains prefetch; publishes buf cur^1
    cur ^= 1;
  }
  // epilogue: lane owns q-row (qrow0+q), cols d = t*16+g*4+{0..3} -> f32x4
  {
    float inv = 1.f / lr;
    size_t base = ((size_t)b * T_ + qrow0 + q) * D_ + h * 64 + g * 4;
    #pragma unroll
    for (int t = 0; t < 4; t++) {
      f32x4 r = *(const f32x4*)(xv + base + t * 16);
      f32x4 o;
      #pragma unroll
      for (int i = 0; i < 4; i++) o[i] = r[i] + acc[t][i] * inv;
      *(f32x4*)(X + base + t * 16) = o;
    }
  }
}

// ------------------------------- launch -------------------------------
extern "C" void kernel_launch(void* const* d_in, const int* in_sizes, int n_in,
                              void* d_out, int out_size, void* d_ws, size_t ws_size,
                              hipStream_t stream) {
  const int*   x_type   = (const int*)d_in[0];
  const float* x_value  = (const float*)d_in[1];
  const float* seq      = (const float*)d_in[2];
  const float* W_attn   = (const float*)d_in[3];
  const float* type_emb = (const float*)d_in[4];
  const float* ln1_g    = (const float*)d_in[5];
  const float* ln1_b    = (const float*)d_in[6];
  const float* ln2_g    = (const float*)d_in[7];
  const float* ln2_b    = (const float*)d_in[8];
  const float* W1       = (const float*)d_in[9];
  const float* b1       = (const float*)d_in[10];
  const float* W2       = (const float*)d_in[11];
  const float* b2       = (const float*)d_in[12];
  float* out = (float*)d_out;
  char* ws = (char*)d_ws;

  // workspace layout — total ~38.5 MiB
  u16*   WtA  = (u16*)(ws + 0);             // 1536x512 bf16  1.5 MiB
  u16*   W1i  = (u16*)(ws + 1572864);       // 2048x512 bf16 interleaved a/gate  2 MiB
  u16*   W2t  = (u16*)(ws + 3670016);       // 512x1024 bf16  1 MiB
  float* rqc  = (float*)(ws + 4718592);     // 4 rope tables, 512 KiB each
  float* rqs  = (float*)(ws + 5242880);
  float* rkc  = (float*)(ws + 5767168);
  float* rks  = (float*)(ws + 6291456);
  u16*   hbuf = (u16*)(ws + 6815744);       // 8192x512 bf16 (h, then h2)  8 MiB
  u16*   qTb  = (u16*)(ws + 15204352);      // (B,H,T,64) bf16  8 MiB
  u16*   kTb  = (u16*)(ws + 23592960);      // 8 MiB
  u16*   vTb  = (u16*)(ws + 31981568);      // (B,H,64,T) bf16  8 MiB
  u16*   ff1a = (u16*)(ws + 15204352);      // 8192x1024 bf16 16 MiB, aliases qT+kT (dead post-attn)

  prep_kernel<<<3136, 256, 0, stream>>>(W_attn, W1, W2, seq, WtA, W1i, W2t,
                                        rqc, rqs, rkc, rks,
                                        x_value, ln1_g, ln1_b, hbuf);
  gemm_qkv<<<768, 256, 0, stream>>>(hbuf, WtA, x_type, type_emb,
                                    rqc, rqs, rkc, rks, qTb, kTb, vTb);
  attn_kernel<<<512, 512, 0, stream>>>(qTb, kTb, vTb, x_value, out);
  ln_kernel<<<B_ * T_ / 4, 256, 0, stream>>>(out, ln2_g, ln2_b, hbuf);
  gemm_ff1<<<512, 512, 0, stream>>>(hbuf, W1i, b1, ff1a);
  gemm_ff2<<<256, 512, 0, stream>>>(ff1a, W2t, b2, out);
}

// Round 17
// 115.976 us; speedup vs baseline: 1.2096x; 1.0270x over previous
//
#include <hip/hip_runtime.h>
#include <stdint.h>
#include <math.h>

typedef unsigned short u16;
typedef unsigned int u32;
typedef __attribute__((ext_vector_type(8))) short bf16x8;   // 8 bf16 (4 VGPRs) MFMA A/B frag
typedef __attribute__((ext_vector_type(4))) float f32x4;
typedef __attribute__((ext_vector_type(2))) float f32x2;
typedef __attribute__((ext_vector_type(2))) u16 u16x2;
typedef __attribute__((ext_vector_type(8))) u16 u16x8;
typedef __attribute__((ext_vector_type(2))) u32 u32x2;

#define B_ 8
#define T_ 1024
#define D_ 512
#define H_ 8
#define TP1 1025
// q scale: 1/sqrt(64) * log2(e)  (softmax runs in exp2 domain)
#define QSCALE 0.1803368801111204f

__device__ __forceinline__ u16 f2b(float f) {           // f32 -> bf16 RNE
  union { float f; u32 u; } v; v.f = f;
  return (u16)((v.u + 0x7fffu + ((v.u >> 16) & 1u)) >> 16);
}
__device__ __forceinline__ void gld16(const void* g, void* l) {
  // async global->LDS, 16B/lane; LDS dest = wave-uniform base + lane*16
  __builtin_amdgcn_global_load_lds((const __attribute__((address_space(1))) u32*)g,
                                   (__attribute__((address_space(3))) u32*)l, 16, 0, 0);
}
__device__ __forceinline__ f32x4 mfma16(bf16x8 a, bf16x8 b, f32x4 c) {
  return __builtin_amdgcn_mfma_f32_16x16x32_bf16(a, b, c, 0, 0, 0);
}
__device__ __forceinline__ u32 cvtpk(float lo, float hi) {   // 2xf32 -> packed bf16x2 (RNE)
  u32 r;
  asm("v_cvt_pk_bf16_f32 %0, %1, %2" : "=v"(r) : "v"(lo), "v"(hi));
  return r;
}
union U8 { u32 u[4]; bf16x8 v; };

// counted-vmcnt waits: wait for the OLDEST stage only, keep the rest in flight
#define WAITV(N) asm volatile("s_waitcnt vmcnt(" #N ")" ::: "memory")

// ---------------- fused prep: weight transposes + rope tables + LN1 ----------------
// blocks 0..575 weight transposes, 576..1087 rope, 1088..3135 LN1 (x_value -> hbuf)
__global__ __launch_bounds__(256) void prep_kernel(const float* __restrict__ W_attn,
    const float* __restrict__ W1, const float* __restrict__ W2,
    const float* __restrict__ seq,
    u16* __restrict__ WtA, u16* __restrict__ W1i, u16* __restrict__ W2t,
    float* __restrict__ cq, float* __restrict__ sq_,
    float* __restrict__ ck, float* __restrict__ sk,
    const float* __restrict__ xv, const float* __restrict__ ln1g,
    const float* __restrict__ ln1b, u16* __restrict__ hbuf) {
  int bid = blockIdx.x, tid = threadIdx.x;
  if (bid >= 1088) {                       // LN1: 8192 rows, 4 rows/block
    int row = (bid - 1088) * 4 + (tid >> 6);
    int lane = tid & 63;
    const float* xr = xv + (size_t)row * D_ + lane * 8;
    f32x4 v0 = *(const f32x4*)xr;
    f32x4 v1 = *(const f32x4*)(xr + 4);
    float s = 0.f, sq = 0.f;
    #pragma unroll
    for (int j = 0; j < 4; j++) { s += v0[j] + v1[j]; sq += v0[j] * v0[j] + v1[j] * v1[j]; }
    #pragma unroll
    for (int m = 1; m < 64; m <<= 1) { s += __shfl_xor(s, m); sq += __shfl_xor(sq, m); }
    float mean = s * (1.f / D_);
    float var = sq * (1.f / D_) - mean * mean;
    float rstd = rsqrtf(var + 1e-5f);
    f32x4 g0 = *(const f32x4*)(ln1g + lane * 8);
    f32x4 g1 = *(const f32x4*)(ln1g + lane * 8 + 4);
    f32x4 b0 = *(const f32x4*)(ln1b + lane * 8);
    f32x4 b1 = *(const f32x4*)(ln1b + lane * 8 + 4);
    u16x8 o;
    #pragma unroll
    for (int j = 0; j < 4; j++) {
      o[j]     = f2b((v0[j] - mean) * rstd * g0[j] + b0[j]);
      o[4 + j] = f2b((v1[j] - mean) * rstd * g1[j] + b1[j]);
    }
    *(u16x8*)(hbuf + (size_t)row * D_ + lane * 8) = o;
    return;
  }
  if (bid >= 576) {                        // rope: B*T*16 elements
    int i = (bid - 576) * 256 + tid;
    int p = i & 15, bt = i >> 4, b = bt >> 10, t = bt & 1023;
    float inv = expf(-(float)p * 0.5756462732485115f);   // 10000^(-p/16)
    float aq = seq[b * TP1 + t] * inv;
    float ak = seq[b * TP1 + t + 1] * inv;
    cq[i] = cosf(aq); sq_[i] = sinf(aq);
    ck[i] = cosf(ak); sk[i] = sinf(ak);
    return;
  }
  __shared__ u16 lt[64][65];
  const float* src; u16* dst; int ld, Kd, k0, r0; bool ilv = false;
  if (bid < 192) {            // WtA: 8 k-tiles x 24 n-tiles
    src = W_attn; dst = WtA; ld = 1536; Kd = 512;
    k0 = (bid & 7) * 64; r0 = (bid >> 3) * 64;
  } else if (bid < 448) {     // W1i: 8 k-tiles x 32 r-tiles, interleaved
    int t = bid - 192;
    src = W1; dst = W1i; ld = 2048; Kd = 512; ilv = true;
    k0 = (t & 7) * 64; r0 = (t >> 3) * 64;
  } else {                    // W2t: 16 k-tiles x 8 n-tiles
    int t = bid - 448;
    src = W2; dst = W2t; ld = 512; Kd = 1024;
    k0 = (t & 15) * 64; r0 = (t >> 4) * 64;
  }
  int nl = tid & 63;
  int scol, rloc;
  if (ilv) {
    if (nl < 32) { scol = (r0 >> 1) + nl;          rloc = ((nl >> 4) << 5) + (nl & 15); }
    else         { scol = 1024 + (r0 >> 1) + (nl - 32); rloc = (((nl - 32) >> 4) << 5) + 16 + (nl & 15); }
  } else { scol = r0 + nl; rloc = nl; }
  #pragma unroll
  for (int it = 0; it < 16; it++) {
    int kl = (tid >> 6) * 16 + it;
    lt[rloc][kl] = f2b(src[(size_t)(k0 + kl) * ld + scol]);
  }
  __syncthreads();
  #pragma unroll
  for (int it = 0; it < 16; it++) {
    int rl = (tid >> 6) * 16 + it;
    dst[(size_t)(r0 + rl) * Kd + k0 + nl] = lt[rl][nl];
  }
}

// ---------------- LayerNorm (ln2): one WAVE per row, no LDS, no barriers ----------------
__global__ __launch_bounds__(256) void ln_kernel(const float* __restrict__ x,
    const float* __restrict__ g, const float* __restrict__ bta, u16* __restrict__ out) {
  int row = blockIdx.x * 4 + (threadIdx.x >> 6);    // 8192 rows, 4 rows/block
  int lane = threadIdx.x & 63;
  const float* xr = x + (size_t)row * D_ + lane * 8;
  f32x4 v0 = *(const f32x4*)xr;
  f32x4 v1 = *(const f32x4*)(xr + 4);
  float s = 0.f, sq = 0.f;
  #pragma unroll
  for (int j = 0; j < 4; j++) { s += v0[j] + v1[j]; sq += v0[j] * v0[j] + v1[j] * v1[j]; }
  #pragma unroll
  for (int m = 1; m < 64; m <<= 1) { s += __shfl_xor(s, m); sq += __shfl_xor(sq, m); }
  float mean = s * (1.f / D_);
  float var = sq * (1.f / D_) - mean * mean;
  float rstd = rsqrtf(var + 1e-5f);
  f32x4 g0 = *(const f32x4*)(g + lane * 8);
  f32x4 g1 = *(const f32x4*)(g + lane * 8 + 4);
  f32x4 b0 = *(const f32x4*)(bta + lane * 8);
  f32x4 b1 = *(const f32x4*)(bta + lane * 8 + 4);
  u16x8 o;
  #pragma unroll
  for (int j = 0; j < 4; j++) {
    o[j]     = f2b((v0[j] - mean) * rstd * g0[j] + b0[j]);
    o[4 + j] = f2b((v1[j] - mean) * rstd * g1[j] + b1[j]);
  }
  *(u16x8*)(out + (size_t)row * D_ + lane * 8) = o;
}

// ---------------- QKV GEMM: 128x128, 4 waves, 3-deep counted pipeline ----------------
// Fused epilogue: type-emb + RoPE + scale + head layout. ALL regions store via
// LDS transpose (staging LDS dead after K-loop) with coalesced u16x8 stores.
__global__ __launch_bounds__(256) void gemm_qkv(const u16* __restrict__ A,
    const u16* __restrict__ Bt,
    const int* __restrict__ x_type, const float* __restrict__ type_emb,
    const float* __restrict__ rqc, const float* __restrict__ rqs,
    const float* __restrict__ rkc, const float* __restrict__ rks,
    u16* __restrict__ qT, u16* __restrict__ kT, u16* __restrict__ vT) {
  __shared__ u16 lsmem[6 * 4096];          // 48KB: lA[3][4096] | lB[3][4096]
  u16* lA = lsmem;
  u16* lB = lsmem + 3 * 4096;
  const int K = 512, NK = 16;
  const int tid = threadIdx.x, lane = tid & 63, w = tid >> 6;
  const int wm = w >> 1, wn = w & 1;
  int swz = (blockIdx.x & 7) * 96 + (blockIdx.x >> 3);
  int byy = swz / 12, bxx = swz - byy * 12;
  const size_t bm = (size_t)byy * 128;
  const size_t bn = (size_t)bxx * 128;

  const int r0 = tid >> 2;
  const int cs = ((tid & 3) ^ ((r0 >> 1) & 3)) * 8;
  const u16* a0 = A + (bm + r0) * K + cs;
  const u16* a1 = A + (bm + 64 + r0) * K + cs;
  const u16* b0 = Bt + (bn + r0) * K + cs;
  const u16* b1p = Bt + (bn + 64 + r0) * K + cs;

  int aoff[4], boff[4];
  #pragma unroll
  for (int i = 0; i < 4; i++) {
    int ra = wm * 64 + i * 16 + (lane & 15);
    aoff[i] = ra * 64 + (((lane >> 4) ^ ((ra >> 1) & 3)) * 16);
    int rb = wn * 64 + i * 16 + (lane & 15);
    boff[i] = rb * 64 + (((lane >> 4) ^ ((rb >> 1) & 3)) * 16);
  }

  auto stage = [&](int j, int buf) {      // 4 loads
    char* ad = (char*)lA + buf * 8192 + w * 1024;
    char* bd = (char*)lB + buf * 8192 + w * 1024;
    gld16(a0 + j * 32, ad);
    gld16(a1 + j * 32, ad + 4096);
    gld16(b0 + j * 32, bd);
    gld16(b1p + j * 32, bd + 4096);
  };
  f32x4 acc[4][4] = {};
  auto compute = [&](int buf) {
    const char* lAc = (const char*)lA + buf * 8192;
    const char* lBc = (const char*)lB + buf * 8192;
    bf16x8 af[4], bf[4];
    #pragma unroll
    for (int i = 0; i < 4; i++) af[i] = *(const bf16x8*)(lAc + aoff[i]);
    #pragma unroll
    for (int n = 0; n < 4; n++) bf[n] = *(const bf16x8*)(lBc + boff[n]);
    __builtin_amdgcn_s_setprio(1);
    #pragma unroll
    for (int i = 0; i < 4; i++)
      #pragma unroll
      for (int n = 0; n < 4; n++)
        acc[i][n] = mfma16(af[i], bf[n], acc[i][n]);
    __builtin_amdgcn_s_setprio(0);
  };

  stage(0, 0);
  stage(1, 1);
  int cur = 0;
  for (int j = 0; j < NK - 1; j++) {
    WAITV(4);                              // oldest stage landed; next stays in flight
    __builtin_amdgcn_s_barrier();
    if (j + 2 < NK) { int nb = cur + 2; if (nb >= 3) nb -= 3; stage(j + 2, nb); }
    compute(cur);
    cur = (cur + 1 == 3) ? 0 : cur + 1;
  }
  WAITV(0);
  __builtin_amdgcn_s_barrier();
  compute(cur);

  // fused epilogue. block-uniform region: 0=q (cols 0..511), 1=k, 2=v
  const int region = (int)(bn >> 9);
  __syncthreads();                         // staging LDS dead -> reuse as transpose buf
  u16 (*tbuf)[136] = (u16(*)[136])lsmem;   // 128 x 136 u16 = 34816B <= 48KB
  const int bb = (int)(bm >> 10);
  const int t0 = (int)(bm & 1023);

  if (region < 2) {
    // compute fused value, write TRANSPOSED layout tbuf[t_local][col_local]
    #pragma unroll
    for (int i = 0; i < 4; i++) {
      #pragma unroll
      for (int jj = 0; jj < 4; jj++) {
        int rl = wm * 64 + i * 16 + (lane >> 4) * 4 + jj;   // t-local
        int row = (int)bm + rl;                             // bt index
        int b = row >> 10, t = row & 1023;
        int ty = x_type[b * TP1 + t + region];              // +0 for q, +1 for k
        const float* rc = (region == 0) ? rqc : rkc;
        const float* rs = (region == 0) ? rqs : rks;
        #pragma unroll
        for (int n = 0; n < 4; n++) {
          int cl = wn * 64 + n * 16 + (lane & 15);          // col-local 0..127
          int cloc = ((int)bn - region * 512) + cl;         // 0..511
          int hd = cloc & 63;
          float v = acc[i][n][jj] + type_emb[(size_t)ty * 1024 + region * 512 + cloc];
          float vp = __shfl_xor(v, 1);
          if (hd < 32) {
            int p = hd >> 1;
            float c = rc[row * 16 + p], s = rs[row * 16 + p];
            v = (hd & 1) ? (v * c + vp * s) : (v * c - vp * s);
          }
          if (region == 0) v *= QSCALE;
          tbuf[rl][cl] = f2b(v);
        }
      }
    }
    __syncthreads();
    // coalesced store: 2048 x 16B chunks; chunk -> (t_local, col_chunk)
    u16* dst = (region == 0) ? qT : kT;
    const int h0 = (((int)bn - region * 512) >> 6);         // first of 2 heads
    #pragma unroll
    for (int p = 0; p < 8; p++) {
      int chunk = p * 256 + tid;
      int tl = chunk >> 4;                                  // 0..127
      int cc = (chunk & 15) * 8;                            // 0..120
      u16x8 o = *(const u16x8*)&tbuf[tl][cc];
      *(u16x8*)(dst + ((size_t)(bb * 8 + h0 + (cc >> 6)) * T_ + t0 + tl) * 64 +
                (cc & 63)) = o;
    }
  } else {
    // V region: transpose to hd-major, coalesced u16x8 stores into vT
    #pragma unroll
    for (int i = 0; i < 4; i++) {
      #pragma unroll
      for (int n = 0; n < 4; n++) {
        int cl = wn * 64 + n * 16 + (lane & 15);       // v-col local 0..127
        #pragma unroll
        for (int jj = 0; jj < 4; jj++) {
          int r = wm * 64 + i * 16 + (lane >> 4) * 4 + jj;   // t local 0..127
          tbuf[cl][r] = f2b(acc[i][n][jj]);
        }
      }
    }
    __syncthreads();
    const int h0 = ((int)bn - 1024) >> 6;              // first head (of 2) in this block
    const size_t rbase = (size_t)(bb * 8 + h0) * 64;   // vT row of cl=0
    #pragma unroll
    for (int p = 0; p < 8; p++) {
      int rl = p * 16 + (tid >> 4);                    // 0..127 (hd-major local)
      int c8 = (tid & 15) * 8;                         // t chunk
      u16x8 o = *(const u16x8*)&tbuf[rl][c8];
      *(u16x8*)(vT + (rbase + rl) * T_ + t0 + c8) = o;
    }
  }
}

// ---------------- FF1 GEMM: BM=256 x BN=128, BK=32, 512 thr / 8 waves, 2-phase ----------------
// SwiGLU epilogue routed through dead staging LDS for coalesced u16x8 stores.
__global__ __launch_bounds__(512) void gemm_ff1(const u16* __restrict__ A,
    const u16* __restrict__ Bt, const float* __restrict__ b1,
    u16* __restrict__ outp) {
  __shared__ u16 lsmem[24576];             // 48KB: lA 2x8192 | lB 2x4096
  u16* lA = lsmem;                         // [2][8192]
  u16* lB = lsmem + 16384;                 // [2][4096]
  const int K = 512;
  const int tid = threadIdx.x, lane = tid & 63, w = tid >> 6;   // 8 waves
  const int wm = w >> 2, wn = w & 3;
  int swz = (blockIdx.x & 7) * 64 + (blockIdx.x >> 3);          // 512 blocks
  int byy = swz >> 4, bxx = swz & 15;                           // 32 x 16
  const size_t bm = (size_t)byy * 256;
  const size_t bn = (size_t)bxx * 128;

  const int r0 = tid >> 2;                                      // 0..127
  const int cs = ((tid & 3) ^ ((r0 >> 1) & 3)) * 8;
  const u16* a0 = A + (bm + r0) * K + cs;
  const u16* a1 = A + (bm + 128 + r0) * K + cs;
  const u16* b0 = Bt + (bn + r0) * K + cs;

  int aoff[8], boff[2];
  #pragma unroll
  for (int i = 0; i < 8; i++) {
    int ra = wm * 128 + i * 16 + (lane & 15);
    aoff[i] = ra * 64 + (((lane >> 4) ^ ((ra >> 1) & 3)) * 16);
  }
  #pragma unroll
  for (int n = 0; n < 2; n++) {
    int rb = wn * 32 + n * 16 + (lane & 15);
    boff[n] = rb * 64 + (((lane >> 4) ^ ((rb >> 1) & 3)) * 16);
  }

  auto stage = [&](int k0, int buf) {      // 3 gld16 calls (8KB each)
    char* ad = (char*)lA + buf * 16384 + w * 1024;
    char* bd = (char*)lB + buf * 8192 + w * 1024;
    gld16(a0 + k0, ad);                    // A rows 0..127
    gld16(a1 + k0, ad + 8192);             // A rows 128..255
    gld16(b0 + k0, bd);                    // B rows 0..127
  };

  f32x4 acc[8][2] = {};
  stage(0, 0);
  __syncthreads();
  int cur = 0;
  for (int k0 = 0; k0 < K; k0 += 32) {
    if (k0 + 32 < K) stage(k0 + 32, cur ^ 1);
    const char* lAc = (const char*)lA + cur * 16384;
    const char* lBc = (const char*)lB + cur * 8192;
    bf16x8 bf[2];
    #pragma unroll
    for (int n = 0; n < 2; n++) bf[n] = *(const bf16x8*)(lBc + boff[n]);
    __builtin_amdgcn_s_setprio(1);
    #pragma unroll
    for (int i = 0; i < 8; i++) {
      bf16x8 af = *(const bf16x8*)(lAc + aoff[i]);
      acc[i][0] = mfma16(af, bf[0], acc[i][0]);
      acc[i][1] = mfma16(af, bf[1], acc[i][1]);
    }
    __builtin_amdgcn_s_setprio(0);
    __syncthreads();
    cur ^= 1;
  }
  // SwiGLU epilogue through dead staging LDS: tbuf[row_local 256][col_local 64+pad]
  __syncthreads();
  u16 (*tbuf)[72] = (u16(*)[72])lsmem;     // 256 x 72 u16 = 36864B <= 48KB, 16B rows
  {
    int cl = wn * 16 + (lane & 15);        // col-local 0..63
    int c = ((int)bn >> 1) + cl;
    float bav = b1[c], bgv = b1[1024 + c];
    #pragma unroll
    for (int i = 0; i < 8; i++) {
      #pragma unroll
      for (int jj = 0; jj < 4; jj++) {
        int rl = wm * 128 + i * 16 + (lane >> 4) * 4 + jj;
        float av = acc[i][0][jj] + bav;
        float gv = acc[i][1][jj] + bgv;
        float sg = gv / (1.f + expf(-gv));
        tbuf[rl][cl] = f2b(sg * av);
      }
    }
  }
  __syncthreads();
  {
    const int c0 = ((int)bn >> 1);
    #pragma unroll
    for (int p = 0; p < 4; p++) {
      int ch = p * 512 + tid;              // 2048 chunks
      int rl = ch >> 3;                    // 0..255
      int cc = (ch & 7) * 8;               // 0..56
      u16x8 o = *(const u16x8*)&tbuf[rl][cc];
      *(u16x8*)(outp + (size_t)((int)bm + rl) * 1024 + c0 + cc) = o;
    }
  }
}

// ---------------- FF2 GEMM: 128x128, BK=64 (two 32-col sub-tiles), 2-phase ----------------
// 512 thr / 8 waves (2x4, 64x32 per wave); 16 barrier iterations (was 32);
// 16 MFMA/wave/iter. LDS 32KB; occupancy stays wave-slot-capped at 4 blocks/CU.
__global__ __launch_bounds__(512) void gemm_ff2(const u16* __restrict__ A,
    const u16* __restrict__ Bt, const float* __restrict__ bias,
    float* __restrict__ C) {
  __shared__ u16 lA[2][8192];              // [buf][kh0 8KB | kh1 8KB]
  __shared__ u16 lB[2][8192];
  const int K = 1024, N = 512, NJ = 16;
  const int tid = threadIdx.x, lane = tid & 63, w = tid >> 6;   // w 0..7
  const int wm = w >> 2, wn = w & 3;                            // 2x4 waves: 64x32 each
  int swz = (blockIdx.x & 7) * 32 + (blockIdx.x >> 3);          // 256 blocks
  int byy = swz >> 2, bxx = swz & 3;
  const size_t bm = (size_t)byy * 128;
  const size_t bn = (size_t)bxx * 128;

  const int r0 = tid >> 2;                                      // 0..127
  const int cs = ((tid & 3) ^ ((r0 >> 1) & 3)) * 8;
  const u16* a0 = A + (bm + r0) * K + cs;
  const u16* b0 = Bt + (bn + r0) * K + cs;

  int aoff[4], boff[2];
  #pragma unroll
  for (int i = 0; i < 4; i++) {
    int ra = wm * 64 + i * 16 + (lane & 15);
    aoff[i] = ra * 64 + (((lane >> 4) ^ ((ra >> 1) & 3)) * 16);
  }
  #pragma unroll
  for (int n = 0; n < 2; n++) {
    int rb = wn * 32 + n * 16 + (lane & 15);
    boff[n] = rb * 64 + (((lane >> 4) ^ ((rb >> 1) & 3)) * 16);
  }

  auto stage = [&](int j, int buf) {       // BK=64: 4 gld16 (two 32-col sub-tiles)
    #pragma unroll
    for (int kh = 0; kh < 2; kh++) {
      int ko = j * 64 + kh * 32;
      gld16(a0 + ko, (char*)lA + buf * 16384 + kh * 8192 + w * 1024);
      gld16(b0 + ko, (char*)lB + buf * 16384 + kh * 8192 + w * 1024);
    }
  };
  f32x4 acc[4][2] = {};
  auto compute = [&](int buf) {
    #pragma unroll
    for (int kh = 0; kh < 2; kh++) {
      const char* lAc = (const char*)lA + buf * 16384 + kh * 8192;
      const char* lBc = (const char*)lB + buf * 16384 + kh * 8192;
      bf16x8 af[4], bf[2];
      #pragma unroll
      for (int i = 0; i < 4; i++) af[i] = *(const bf16x8*)(lAc + aoff[i]);
      #pragma unroll
      for (int n = 0; n < 2; n++) bf[n] = *(const bf16x8*)(lBc + boff[n]);
      __builtin_amdgcn_s_setprio(1);
      #pragma unroll
      for (int i = 0; i < 4; i++)
        #pragma unroll
        for (int n = 0; n < 2; n++)
          acc[i][n] = mfma16(af[i], bf[n], acc[i][n]);
      __builtin_amdgcn_s_setprio(0);
    }
  };

  stage(0, 0);
  __syncthreads();
  int cur = 0;
  for (int j = 0; j < NJ; j++) {
    if (j + 1 < NJ) stage(j + 1, cur ^ 1);     // prefetch overlaps compute below
    compute(cur);
    __syncthreads();                           // drains prefetch; publishes buf cur^1
    cur ^= 1;
  }

  #pragma unroll
  for (int i = 0; i < 4; i++) {
    size_t mrow = bm + wm * 64 + i * 16 + (lane >> 4) * 4;
    #pragma unroll
    for (int n = 0; n < 2; n++) {
      size_t col = bn + wn * 32 + n * 16 + (lane & 15);
      float bv = bias[col];
      #pragma unroll
      for (int jj = 0; jj < 4; jj++) {
        size_t idx = (mrow + jj) * (size_t)N + col;
        C[idx] = acc[i][n][jj] + bv + C[idx];   // in-place residual
      }
    }
  }
}

// ---------------- causal flash attention + residual: out = x_value + attn ----------------
// 8 waves / 512 thr / 128 q-rows, 2-phase LDS dbuf with KVBLK=128 (two proven 8KB
// sub-tiles per buffer): jmax = qp+1 barrier-locked iterations (max 8).
__global__ __launch_bounds__(512, 4) void attn_kernel(const u16* __restrict__ qT,
    const u16* __restrict__ kT, const u16* __restrict__ vT,
    const float* __restrict__ xv, float* __restrict__ X) {
  int s0 = (blockIdx.x & 7) * 64 + (blockIdx.x >> 3);   // 512 blocks, 8 bh per XCD
  const int bh = ((blockIdx.x & 7) << 3) + (s0 & 7);    // 8 bh per XCD
  const int qp = 7 - ((s0 >> 3) & 7);                   // true LPT: qp=7 of all bh first
  const int b = bh >> 3, h = bh & 7;
  const int tid = threadIdx.x, lane = tid & 63, w = tid >> 6;   // 8 waves
  const int q = lane & 15, g = lane >> 4;
  __shared__ u16 lK[2][8192];              // [buf][half0 8KB | half1 8KB]
  __shared__ u16 lV[2][8192];

  const int qrow0 = qp * 128 + w * 16;     // this wave's 16-row q-strip
  bf16x8 qf[2];
  {
    const u16* qp_ = qT + ((size_t)bh * T_ + qrow0 + q) * 64 + g * 8;
    qf[0] = *(const bf16x8*)qp_;
    qf[1] = *(const bf16x8*)(qp_ + 32);
  }
  f32x4 acc[4] = {};
  float mr = -1e30f, lr = 0.f;

  const int sr = tid >> 3;                 // 0..63
  const int scs = ((tid & 7) ^ (sr & 7)) * 8;
  const u16* kb = kT + ((size_t)bh * T_ + sr) * 64 + scs;
  const u16* vb = vT + ((size_t)bh * 64 + sr) * T_ + scs;

  auto stage = [&](int j, int buf) {       // K rows [j*128,+128), V cols [j*128,+128)
    char* kd = (char*)lK + buf * 16384 + w * 1024;
    char* vd = (char*)lV + buf * 16384 + w * 1024;
    gld16(kb + (size_t)j * 8192, kd);              // K half0 (rows +0..63)
    gld16(kb + (size_t)j * 8192 + 4096, kd + 8192);// K half1 (rows +64..127)
    gld16(vb + j * 128, vd);                       // V half0 (cols +0..63)
    gld16(vb + j * 128 + 64, vd + 8192);           // V half1 (cols +64..127)
  };

  const int jmax = qp + 1;
  stage(0, 0);
  __syncthreads();
  int cur = 0;
  for (int j = 0; j < jmax; j++) {
    if (j + 1 < jmax) stage(j + 1, cur ^ 1);   // prefetch next 128-tile under compute
    const char* lKc = (const char*)lK + cur * 16384;
    const char* lVc = (const char*)lV + cur * 16384;

    // QK^T swapped: s[n][i] = S[key = j*128 + n*16+g*4+i][qrow0+q]
    f32x4 s[8] = {};
    __builtin_amdgcn_s_setprio(1);
    #pragma unroll
    for (int ka = 0; ka < 2; ka++) {
      #pragma unroll
      for (int n = 0; n < 8; n++) {
        bf16x8 kf = *(const bf16x8*)(lKc + (n >> 2) * 8192 + ((n & 3) * 16 + q) * 128 +
                                     (((ka * 4 + g) ^ (q & 7)) * 16));
        s[n] = mfma16(kf, qf[ka], s[n]);
      }
    }
    __builtin_amdgcn_s_setprio(0);
    if (j == jmax - 1) {                   // diagonal-tile causal mask
      int qrow = w * 16 + q;               // key-local: n*16+g*4+i > w*16+q
      #pragma unroll
      for (int n = 0; n < 8; n++)
        #pragma unroll
        for (int i = 0; i < 4; i++)
          if (n * 16 + g * 4 + i > qrow) s[n][i] = -1e30f;
    }
    // in-register softmax: one q-row per lane (+2 shfl across g-groups)
    float mt = -1e30f;
    #pragma unroll
    for (int n = 0; n < 8; n++)
      mt = fmaxf(mt, fmaxf(fmaxf(s[n][0], s[n][1]), fmaxf(s[n][2], s[n][3])));
    mt = fmaxf(mt, __shfl_xor(mt, 16));
    mt = fmaxf(mt, __shfl_xor(mt, 32));
    if (__any(mt > mr + 8.f)) {            // defer-max: skip rescale when growth < 2^8
      float mnew = fmaxf(mr, mt);
      float sc = exp2f(mr - mnew);
      mr = mnew;
      lr *= sc;
      #pragma unroll
      for (int t = 0; t < 4; t++) acc[t] *= sc;
    }
    float ps = 0.f;
    U8 pa[4];                              // pa[kt] covers keys kt*32..kt*32+31
    #pragma unroll
    for (int kt = 0; kt < 4; kt++) {
      float p0[4], p1[4];
      #pragma unroll
      for (int i = 0; i < 4; i++) {
        p0[i] = exp2f(s[2 * kt][i] - mr);
        p1[i] = exp2f(s[2 * kt + 1][i] - mr);
        ps += p0[i] + p1[i];
      }
      pa[kt].u[0] = cvtpk(p0[0], p0[1]);
      pa[kt].u[1] = cvtpk(p0[2], p0[3]);
      pa[kt].u[2] = cvtpk(p1[0], p1[1]);
      pa[kt].u[3] = cvtpk(p1[2], p1[3]);
    }
    ps += __shfl_xor(ps, 16);
    ps += __shfl_xor(ps, 32);
    lr += ps;
    // PV: O^T[d][q] += V^T[d][k'] P^T[k'][q]; kt half = kt>>1, sub-chunk = kt&1
    __builtin_amdgcn_s_setprio(1);
    #pragma unroll
    for (int t = 0; t < 4; t++) {
      #pragma unroll
      for (int kt = 0; kt < 4; kt++) {
        const char* vrh = lVc + (kt >> 1) * 8192 + (t * 16 + q) * 128 + (g & 1) * 8;
        int ktl = kt & 1;
        u32x2 lo = *(const u32x2*)(vrh + (((ktl * 4 + (g >> 1)) ^ (q & 7)) * 16));
        u32x2 hi = *(const u32x2*)(vrh + (((ktl * 4 + 2 + (g >> 1)) ^ (q & 7)) * 16));
        U8 af;
        af.u[0] = lo[0]; af.u[1] = lo[1]; af.u[2] = hi[0]; af.u[3] = hi[1];
        acc[t] = mfma16(af.v, pa[kt].v, acc[t]);
      }
    }
    __builtin_amdgcn_s_setprio(0);
    __syncthreads();                       // drains prefetch; publishes buf cur^1
    cur ^= 1;
  }
  // epilogue: lane owns q-row (qrow0+q), cols d = t*16+g*4+{0..3} -> f32x4
  {
    float inv = 1.f / lr;
    size_t base = ((size_t)b * T_ + qrow0 + q) * D_ + h * 64 + g * 4;
    #pragma unroll
    for (int t = 0; t < 4; t++) {
      f32x4 r = *(const f32x4*)(xv + base + t * 16);
      f32x4 o;
      #pragma unroll
      for (int i = 0; i < 4; i++) o[i] = r[i] + acc[t][i] * inv;
      *(f32x4*)(X + base + t * 16) = o;
    }
  }
}

// ------------------------------- launch -------------------------------
extern "C" void kernel_launch(void* const* d_in, const int* in_sizes, int n_in,
                              void* d_out, int out_size, void* d_ws, size_t ws_size,
                              hipStream_t stream) {
  const int*   x_type   = (const int*)d_in[0];
  const float* x_value  = (const float*)d_in[1];
  const float* seq      = (const float*)d_in[2];
  const float* W_attn   = (const float*)d_in[3];
  const float* type_emb = (const float*)d_in[4];
  const float* ln1_g    = (const float*)d_in[5];
  const float* ln1_b    = (const float*)d_in[6];
  const float* ln2_g    = (const float*)d_in[7];
  const float* ln2_b    = (const float*)d_in[8];
  const float* W1       = (const float*)d_in[9];
  const float* b1       = (const float*)d_in[10];
  const float* W2       = (const float*)d_in[11];
  const float* b2       = (const float*)d_in[12];
  float* out = (float*)d_out;
  char* ws = (char*)d_ws;

  // workspace layout — total ~38.5 MiB
  u16*   WtA  = (u16*)(ws + 0);             // 1536x512 bf16  1.5 MiB
  u16*   W1i  = (u16*)(ws + 1572864);       // 2048x512 bf16 interleaved a/gate  2 MiB
  u16*   W2t  = (u16*)(ws + 3670016);       // 512x1024 bf16  1 MiB
  float* rqc  = (float*)(ws + 4718592);     // 4 rope tables, 512 KiB each
  float* rqs  = (float*)(ws + 5242880);
  float* rkc  = (float*)(ws + 5767168);
  float* rks  = (float*)(ws + 6291456);
  u16*   hbuf = (u16*)(ws + 6815744);       // 8192x512 bf16 (h, then h2)  8 MiB
  u16*   qTb  = (u16*)(ws + 15204352);      // (B,H,T,64) bf16  8 MiB
  u16*   kTb  = (u16*)(ws + 23592960);      // 8 MiB
  u16*   vTb  = (u16*)(ws + 31981568);      // (B,H,64,T) bf16  8 MiB
  u16*   ff1a = (u16*)(ws + 15204352);      // 8192x1024 bf16 16 MiB, aliases qT+kT (dead post-attn)

  prep_kernel<<<3136, 256, 0, stream>>>(W_attn, W1, W2, seq, WtA, W1i, W2t,
                                        rqc, rqs, rkc, rks,
                                        x_value, ln1_g, ln1_b, hbuf);
  gemm_qkv<<<768, 256, 0, stream>>>(hbuf, WtA, x_type, type_emb,
                                    rqc, rqs, rkc, rks, qTb, kTb, vTb);
  attn_kernel<<<512, 512, 0, stream>>>(qTb, kTb, vTb, x_value, out);
  ln_kernel<<<B_ * T_ / 4, 256, 0, stream>>>(out, ln2_g, ln2_b, hbuf);
  gemm_ff1<<<512, 512, 0, stream>>>(hbuf, W1i, b1, ff1a);
  gemm_ff2<<<256, 512, 0, stream>>>(ff1a, W2t, b2, out);
}